// Round 3
// baseline (333.186 us; speedup 1.0000x reference)
//
#include <hip/hip_runtime.h>

#define Bn 32
#define Cn 64
#define Hn 64
#define Wn 64
#define On 128
#define HP 62
#define WP 62
#define CKn 576
#define Ln (HP*WP)          // 3844
#define Y_ELEMS (Bn*On*Ln)  // 15745024

typedef unsigned int uint32;
typedef unsigned short ushort16;
typedef __bf16 bf16x8 __attribute__((ext_vector_type(8)));
typedef float floatx4 __attribute__((ext_vector_type(4)));

static __device__ __forceinline__ uint32 bf16r(float f){
  uint32 u = __float_as_uint(f);
  return (u + 0x7FFFu + ((u >> 16) & 1u)) >> 16;
}

// ---------------- new-path ws layout (floats) ----------------
#define KSB   4
#define GSZ   (On*CKn)            // 73728
#define NS1   0
#define NS2   128
#define NG    256                 // KSB * GSZ floats = 294912
#define NWNB  (NG + KSB*GSZ)      // 295168
#define NXB   (NWNB + 36864)      // 332032
#define NPB   (NXB + 4194304)     // 4526336  (proven-safe layout)
#define WS_NEED ((size_t)49800000)

__global__ __launch_bounds__(256) void k_norm(const float* __restrict__ w, ushort16* __restrict__ wnb,
                                              float* __restrict__ S1, float* __restrict__ S2,
                                              float* __restrict__ G, int ngbuf){
  int o = blockIdx.x; int t = threadIdx.x;
  for (int kq = 0; kq < ngbuf; kq++)
    for (int k = t; k < CKn; k += 256) G[(size_t)kq*GSZ + o*CKn + k] = 0.f;
  if (t == 0){ S1[o] = 0.f; S2[o] = 0.f; }
  float s = 0.f;
  for (int k = t; k < CKn; k += 256){ float v = w[o*CKn + k]; s += v*v; }
  #pragma unroll
  for (int off = 32; off; off >>= 1) s += __shfl_down(s, off);
  __shared__ float red[4]; __shared__ float sh_inv;
  if ((t & 63) == 0) red[t >> 6] = s;
  __syncthreads();
  if (t == 0){
    float tot = red[0] + red[1] + red[2] + red[3];
    float nrm = sqrtf(tot);
    sh_inv = (nrm == 0.f) ? 1.f : 1.f/nrm;
  }
  __syncthreads();
  float inv = sh_inv;
  for (int k = t; k < CKn; k += 256){
    float v = w[o*CKn + k] * inv;
    int c = k / 9;
    int q = k - c*9;
    wnb[o*CKn + q*64 + c] = (ushort16)bf16r(v);
  }
}

// x fp32 -> bf16, layout unchanged [b][c][h][w]
__global__ __launch_bounds__(256) void k_xb(const float* __restrict__ x, ushort16* __restrict__ xb){
  size_t idx = ((size_t)blockIdx.x*256 + threadIdx.x)*4;
  float4 v = *(const float4*)(x + idx);
  uint2 o;
  o.x = bf16r(v.x) | (bf16r(v.y) << 16);
  o.y = bf16r(v.z) | (bf16r(v.w) << 16);
  *(uint2*)(xb + idx) = o;
}

// MFMA implicit-GEMM conv (unchanged).
__global__ __launch_bounds__(256, 3) void k_convm(const float* __restrict__ x,
                                                  const ushort16* __restrict__ wnb,
                                                  const float* __restrict__ bias,
                                                  float* __restrict__ y){
  __shared__ ushort16 slab[4*64*68];
  __shared__ ushort16 Bl[2][128*36];
  int t = threadIdx.x;
  int lane = t & 63;
  int wv = t >> 6;
  int mtile = blockIdx.x;
  int b = blockIdx.y;
  int i0 = mtile*2;
  {
    int c0 = (t & 31)*2;
    int grp = t >> 5;
    int r = grp >> 1;
    int w0 = (grp & 1)*32;
    const float* p0 = x + (((size_t)b*Cn + c0)*Hn + (i0 + r))*Wn + w0;
    const float* p1 = p0 + (size_t)Hn*Wn;
    #pragma unroll
    for (int ch = 0; ch < 4; ch++){
      float4 A0 = *(const float4*)(p0 + ch*8);
      float4 A1 = *(const float4*)(p0 + ch*8 + 4);
      float4 B0 = *(const float4*)(p1 + ch*8);
      float4 B1 = *(const float4*)(p1 + ch*8 + 4);
      float v0[8] = {A0.x,A0.y,A0.z,A0.w,A1.x,A1.y,A1.z,A1.w};
      float v1[8] = {B0.x,B0.y,B0.z,B0.w,B1.x,B1.y,B1.z,B1.w};
      #pragma unroll
      for (int qq = 0; qq < 8; qq++){
        int wloc = w0 + ch*8 + qq;
        *(uint32*)&slab[(r*64 + wloc)*68 + c0] = (bf16r(v1[qq]) << 16) | bf16r(v0[qq]);
      }
    }
  }
  int ob = t >> 1;
  int kh16 = (t & 1)*16;
  const ushort16* wrow = wnb + (size_t)ob*CKn + kh16;
  {
    uint4 bA = *(const uint4*)(wrow);
    uint4 bB = *(const uint4*)(wrow + 8);
    ushort16* dst = &Bl[0][ob*36 + kh16];
    ((uint2*)dst)[0] = make_uint2(bA.x, bA.y);
    ((uint2*)dst)[1] = make_uint2(bA.z, bA.w);
    ((uint2*)dst)[2] = make_uint2(bB.x, bB.y);
    ((uint2*)dst)[3] = make_uint2(bB.z, bB.w);
  }
  int quad8 = (lane >> 4) << 3;
  int iT[2], jT[2];
  #pragma unroll
  for (int mt = 0; mt < 2; mt++){
    int m = wv*32 + mt*16 + (lane & 15);
    int pos = m < 124 ? m : 123;
    int hi = pos >= 62;
    iT[mt] = hi;
    jT[mt] = pos - (hi ? 62 : 0);
  }
  floatx4 acc[2][8];
  #pragma unroll
  for (int mt = 0; mt < 2; mt++)
    #pragma unroll
    for (int nt = 0; nt < 8; nt++)
      acc[mt][nt] = (floatx4){0.f, 0.f, 0.f, 0.f};
  union U8 { uint2 u[2]; bf16x8 v; };
  for (int s = 0; s < 18; s++){
    uint4 nA, nB;
    if (s < 17){
      nA = *(const uint4*)(wrow + (s+1)*32);
      nB = *(const uint4*)(wrow + (s+1)*32 + 8);
    }
    __syncthreads();
    int k0 = s*32 + quad8;
    int q = k0 >> 6;
    int c0 = k0 & 63;
    int kh = (q*86) >> 8;
    int kw = q - kh*3;
    bf16x8 af[2];
    #pragma unroll
    for (int mt = 0; mt < 2; mt++){
      const ushort16* ap = &slab[((iT[mt] + kh)*64 + jT[mt] + kw)*68 + c0];
      U8 ua;
      ua.u[0] = *(const uint2*)(ap);
      ua.u[1] = *(const uint2*)(ap + 4);
      af[mt] = ua.v;
    }
    const ushort16* bbase = &Bl[s & 1][(lane & 15)*36 + quad8];
    bf16x8 bf[8];
    #pragma unroll
    for (int nt = 0; nt < 8; nt++){
      const ushort16* bp = bbase + nt*576;
      U8 ub;
      ub.u[0] = *(const uint2*)(bp);
      ub.u[1] = *(const uint2*)(bp + 4);
      bf[nt] = ub.v;
    }
    #pragma unroll
    for (int mt = 0; mt < 2; mt++)
      #pragma unroll
      for (int nt = 0; nt < 8; nt++)
        acc[mt][nt] = __builtin_amdgcn_mfma_f32_16x16x32_bf16(af[mt], bf[nt], acc[mt][nt], 0, 0, 0);
    if (s < 17){
      ushort16* dst = &Bl[(s+1) & 1][ob*36 + kh16];
      ((uint2*)dst)[0] = make_uint2(nA.x, nA.y);
      ((uint2*)dst)[1] = make_uint2(nA.z, nA.w);
      ((uint2*)dst)[2] = make_uint2(nB.x, nB.y);
      ((uint2*)dst)[3] = make_uint2(nB.z, nB.w);
    }
  }
  float bv[8];
  #pragma unroll
  for (int nt = 0; nt < 8; nt++) bv[nt] = bias[nt*16 + (lane & 15)];
  #pragma unroll
  for (int mt = 0; mt < 2; mt++){
    #pragma unroll
    for (int reg = 0; reg < 4; reg++){
      int m = wv*32 + mt*16 + (lane >> 4)*4 + reg;
      if (m < 124){
        int hi = m >= 62;
        int ii = i0 + hi;
        int jj = m - (hi ? 62 : 0);
        float* yp = y + (((size_t)b*On)*HP + ii)*WP + jj;
        #pragma unroll
        for (int nt = 0; nt < 8; nt++){
          int o = nt*16 + (lane & 15);
          yp[(size_t)o*Ln] = acc[mt][nt][reg] + bv[nt];
        }
      }
    }
  }
}

// softmax v2 (unchanged)
__global__ __launch_bounds__(256) void k_softp(const float* __restrict__ y, ushort16* __restrict__ pb,
                                               float* __restrict__ S1, float* __restrict__ S2){
  __shared__ float mpart[2][256], dpart[2][256];
  __shared__ float s1loc[128], s2loc[128];
  int b = blockIdx.x;
  int s = blockIdx.y;          // 0..30
  int i0 = s*2;
  int t = threadIdx.x;
  int j = t & 63;
  int og = t >> 6;
  if (t < 128){ s1loc[t] = 0.f; s2loc[t] = 0.f; }
  int je = j < WP ? j : (WP-1);
  const float* yb = y + ((size_t)b*On)*Ln + (size_t)i0*WP + je;
  // pass 1
  float m0 = -3.0e38f, m1 = -3.0e38f, d0 = 0.f, d1 = 0.f;
  for (int oi = 0; oi < 32; oi++){
    int o = og*32 + oi;
    const float* yp = yb + (size_t)o*Ln;
    float v0 = yp[0];
    float v1 = yp[WP];
    float n0 = fmaxf(m0, v0);
    d0 = d0*__expf(m0 - n0) + __expf(v0 - n0);
    m0 = n0;
    float n1 = fmaxf(m1, v1);
    d1 = d1*__expf(m1 - n1) + __expf(v1 - n1);
    m1 = n1;
  }
  mpart[0][t] = m0; dpart[0][t] = d0;
  mpart[1][t] = m1; dpart[1][t] = d1;
  __syncthreads();
  float mc[2], ic[2];
  #pragma unroll
  for (int r = 0; r < 2; r++){
    float ma = mpart[r][j],      mb = mpart[r][64+j];
    float mcc = mpart[r][128+j], md = mpart[r][192+j];
    float mm = fmaxf(fmaxf(ma, mb), fmaxf(mcc, md));
    float dd = dpart[r][j]*__expf(ma-mm) + dpart[r][64+j]*__expf(mb-mm)
             + dpart[r][128+j]*__expf(mcc-mm) + dpart[r][192+j]*__expf(md-mm);
    mc[r] = mm; ic[r] = 1.f/dd;
  }
  // pass 2
  bool act = j < WP;
  for (int oi = 0; oi < 32; oi++){
    int o = og*32 + oi;
    const float* yp = yb + (size_t)o*Ln;
    float r0 = 0.f, r1 = 0.f;
    if (act){
      r0 = __expf(yp[0] - mc[0]) * ic[0];
      r1 = __expf(yp[WP] - mc[1]) * ic[1];
    }
    float p0 = r0*r0, p1 = r1*r1;
    ushort16* pp = pb + (((size_t)b*On + o)*HP + i0)*64 + j;
    pp[0]  = (ushort16)bf16r(p0);
    pp[64] = (ushort16)bf16r(p1);
    float s1v = r0 + r1, s2v = p0 + p1;
    #pragma unroll
    for (int off = 32; off; off >>= 1){ s1v += __shfl_down(s1v, off); s2v += __shfl_down(s2v, off); }
    if (j == 0){ s1loc[o] += s1v; s2loc[o] += s2v; }   // single writer per o per block
  }
  __syncthreads();
  if (t < 128){ atomicAdd(&S1[t], s1loc[t]); atomicAdd(&S2[t], s2loc[t]); }
}

// MFMA delta v4: register-pipelined loop.
// R2 post-mortem: VGPR_Count=40 (compiler targeted 8 waves/SIMD the grid never
// delivers) -> loads serialized by waitcnt, ~2440 cyc/slice vs ~100 cyc work;
// all pipes <9%. Fix: __launch_bounds__(512,4) (128-VGPR budget) + explicit
// depth-1 prefetch of the next slice's 7 loads. 512-thread blocks, grid (32,16):
// 8 waves = 2 b's x 4 K-quarters -> 16 waves/CU (50% cap), atomics 2.36M->1.18M,
// striped 4-way by (by&3).
#define DOKH(dc, ec, off) { \
  U16 f0, f1, f2; \
  f0.q = dc; \
  f1.q = make_uint4((dc.x>>16)|(dc.y<<16), (dc.y>>16)|(dc.z<<16), \
                    (dc.z>>16)|(dc.w<<16), (dc.w>>16)|(ec<<16)); \
  f2.q = make_uint4(dc.y, dc.z, dc.w, ec); \
  acc[(off)+0] = __builtin_amdgcn_mfma_f32_16x16x32_bf16(a_c.v, f0.v, acc[(off)+0], 0, 0, 0); \
  acc[(off)+1] = __builtin_amdgcn_mfma_f32_16x16x32_bf16(a_c.v, f1.v, acc[(off)+1], 0, 0, 0); \
  acc[(off)+2] = __builtin_amdgcn_mfma_f32_16x16x32_bf16(a_c.v, f2.v, acc[(off)+2], 0, 0, 0); \
}

__global__ __launch_bounds__(512, 4) void k_deltam(const ushort16* __restrict__ xb,
                                                   const ushort16* __restrict__ pb,
                                                   float* __restrict__ G){
  __shared__ float Gl[16*144];
  int t = threadIdx.x;
  int lane = t & 63;
  int wv = t >> 6;          // 0..7
  int z = blockIdx.x;       // 0..31: mg = z>>2, ntk = z&3
  int by = blockIdx.y;      // 0..15 (b-pair)
  int mg = z >> 2;
  int ntk = z & 3;
  for (int q = t; q < 16*144; q += 512) Gl[q] = 0.f;
  __syncthreads();
  int cl = lane & 15;
  int quad = lane >> 4;
  int quad8 = quad << 3;
  int b   = by*2 + (wv >> 2);   // 2 b's per block
  int ks0 = (wv & 3)*31;        // 4 K-quarters per b
  const ushort16* pA = pb + ((size_t)b*On + mg*16 + cl)*(HP*64);
  const ushort16* xbase = xb + ((size_t)b*Cn + ntk*16 + cl)*(Hn*Wn);
  floatx4 acc[9];
  #pragma unroll
  for (int nt = 0; nt < 9; nt++) acc[nt] = (floatx4){0.f, 0.f, 0.f, 0.f};
  union U16 { uint4 q; bf16x8 v; };
  // prefetch slice 0
  U16 a_n; uint4 dn0, dn1, dn2; uint32 en0, en1, en2;
  {
    int i = ks0 >> 1;
    int wb = ((ks0 & 1) << 5) + quad8;
    a_n.q = *(const uint4*)(pA + i*64 + wb);
    const ushort16* xr0 = xbase + (i+0)*Wn + wb;
    const ushort16* xr1 = xbase + (i+1)*Wn + wb;
    const ushort16* xr2 = xbase + (i+2)*Wn + wb;
    dn0 = *(const uint4*)xr0; en0 = *(const uint32*)(xr0 + 8);
    dn1 = *(const uint4*)xr1; en1 = *(const uint32*)(xr1 + 8);
    dn2 = *(const uint4*)xr2; en2 = *(const uint32*)(xr2 + 8);
  }
  for (int s = 0; s < 31; s++){
    U16 a_c = a_n;
    uint4 dc0 = dn0, dc1 = dn1, dc2 = dn2;
    uint32 ec0 = en0, ec1 = en1, ec2 = en2;
    if (s < 30){
      int ks = ks0 + s + 1;
      int i = ks >> 1;
      int wb = ((ks & 1) << 5) + quad8;
      a_n.q = *(const uint4*)(pA + i*64 + wb);
      const ushort16* xr0 = xbase + (i+0)*Wn + wb;
      const ushort16* xr1 = xbase + (i+1)*Wn + wb;
      const ushort16* xr2 = xbase + (i+2)*Wn + wb;
      dn0 = *(const uint4*)xr0; en0 = *(const uint32*)(xr0 + 8);
      dn1 = *(const uint4*)xr1; en1 = *(const uint32*)(xr1 + 8);
      dn2 = *(const uint4*)xr2; en2 = *(const uint32*)(xr2 + 8);
    }
    DOKH(dc0, ec0, 0)
    DOKH(dc1, ec1, 3)
    DOKH(dc2, ec2, 6)
  }
  // cross-wave reduce in LDS (8-way atomic), then one global atomic per element
  #pragma unroll
  for (int nt = 0; nt < 9; nt++)
    #pragma unroll
    for (int reg = 0; reg < 4; reg++)
      atomicAdd(&Gl[(quad*4 + reg)*144 + nt*16 + cl], acc[nt][reg]);
  __syncthreads();
  float* Gq = G + (size_t)(by & 3)*GSZ;
  for (int idx = t; idx < 16*144; idx += 512){
    int ol = idx / 144;
    int col = idx - ol*144;
    int q = col >> 4;
    int c = ntk*16 + (col & 15);
    atomicAdd(&Gq[(size_t)(mg*16 + ol)*CKn + q*64 + c], Gl[idx]);
  }
}

__global__ __launch_bounds__(576) void k_finalm(const float* __restrict__ w, const float* __restrict__ G,
                                                const float* __restrict__ S1, const float* __restrict__ S2,
                                                float* __restrict__ dw){
  int o = blockIdx.x; int k = threadIdx.x;
  int c = k / 9;
  int q = k - c*9;
  float s1 = S1[o]; if (s1 == 0.f) s1 = 1.f;
  float g = 0.f;
  #pragma unroll
  for (int kq = 0; kq < KSB; kq++) g += G[(size_t)kq*GSZ + o*CKn + q*64 + c];
  dw[o*CKn + k] = (g - S2[o]*w[o*CKn + k]) / s1;
}

// ---------------- old fallback path ----------------
__global__ __launch_bounds__(256) void k_soft_old(const float* __restrict__ y, float* __restrict__ mbuf,
                                                  float* __restrict__ invdbuf, float* __restrict__ S1,
                                                  float* __restrict__ S2){
  __shared__ float s1loc[128], s2loc[128];
  int t = threadIdx.x;
  if (t < 128){ s1loc[t] = 0.f; s2loc[t] = 0.f; }
  __syncthreads();
  int b = blockIdx.x;
  int i = blockIdx.y*4 + (t >> 6);
  int j = t & 63;
  bool act = (i < 62) && (j < 62);
  const float* yp = y + (((size_t)b*On)*HP + (i < 62 ? i : 0))*WP + j;
  float mx = -3.0e38f;
  if (act){ for (int o = 0; o < On; o++) mx = fmaxf(mx, yp[(size_t)o*Ln]); }
  float den = 0.f;
  if (act){ for (int o = 0; o < On; o++) den += __expf(yp[(size_t)o*Ln] - mx); }
  float inv = act ? 1.f/den : 0.f;
  if (act){
    int pos = (b*HP + i)*WP + j;
    mbuf[pos] = mx; invdbuf[pos] = inv;
  }
  for (int o = 0; o < On; o++){
    float r = act ? __expf(yp[(size_t)o*Ln] - mx)*inv : 0.f;
    float s1v = r, s2v = r*r;
    #pragma unroll
    for (int off = 32; off; off >>= 1){ s1v += __shfl_down(s1v, off); s2v += __shfl_down(s2v, off); }
    if ((t & 63) == 0){ atomicAdd(&s1loc[o], s1v); atomicAdd(&s2loc[o], s2v); }
  }
  __syncthreads();
  if (t < 128){ atomicAdd(&S1[t], s1loc[t]); atomicAdd(&S2[t], s2loc[t]); }
}

__global__ __launch_bounds__(256) void k_delta_old(const float* __restrict__ x, const float* __restrict__ y,
                                                   const float* __restrict__ mbuf, const float* __restrict__ invdbuf,
                                                   float* __restrict__ G){
  __shared__ float planes[3][64][64];
  __shared__ float plds[16][64];
  int o0 = blockIdx.x * 16;
  int bs = blockIdx.y;
  int b = bs >> 2;
  int s = bs & 3;
  int i0 = s * 16;
  int nrows = (s == 3) ? 14 : 16;
  int t = threadIdx.x;
  int lane = t & 63;
  int w = t >> 6;
  int lc = t >> 2;
  int lw0 = (t & 3) << 4;
  const float* xb = x + (size_t)b*(Cn*Hn*Wn) + (size_t)lc*(Hn*Wn) + lw0;
  float acc[4][9];
  #pragma unroll
  for (int oi = 0; oi < 4; oi++)
    #pragma unroll
    for (int q = 0; q < 9; q++) acc[oi][q] = 0.f;
  #pragma unroll
  for (int pp = 0; pp < 2; pp++){
    int ih = i0 + pp;
    const float* src = xb + (size_t)ih*Wn;
    #pragma unroll
    for (int q = 0; q < 16; q++) planes[ih % 3][lw0 + q][lc] = src[q];
  }
  for (int ii = 0; ii < nrows; ii++){
    int i = i0 + ii;
    {
      int ih = i + 2;
      const float* src = xb + (size_t)ih*Wn;
      #pragma unroll
      for (int q = 0; q < 16; q++) planes[ih % 3][lw0 + q][lc] = src[q];
    }
    int R = b*HP + i;
    #pragma unroll
    for (int oi = 0; oi < 4; oi++){
      int o = o0 + w*4 + oi;
      float p = 0.f;
      if (lane < WP){
        int pos = R*WP + lane;
        float yv = y[(((size_t)b*On + o)*HP + i)*WP + lane];
        float r = __expf(yv - mbuf[pos]) * invdbuf[pos];
        p = r*r;
      }
      plds[w*4 + oi][lane] = p;
    }
    __syncthreads();
    int c = lane;
    int s0 = i % 3, s1 = (i+1) % 3, s2g = (i+2) % 3;
    #pragma unroll 1
    for (int jj0 = 0; jj0 < 56; jj0 += 8){
      float xv[3][12];
      #pragma unroll
      for (int q = 0; q < 12; q++){
        xv[0][q] = planes[s0][jj0+q][c];
        xv[1][q] = planes[s1][jj0+q][c];
        xv[2][q] = planes[s2g][jj0+q][c];
      }
      #pragma unroll
      for (int oi = 0; oi < 4; oi++){
        float4 pa = *(const float4*)&plds[w*4+oi][jj0];
        float4 pbq = *(const float4*)&plds[w*4+oi][jj0+4];
        float pv[8] = {pa.x,pa.y,pa.z,pa.w,pbq.x,pbq.y,pbq.z,pbq.w};
        #pragma unroll
        for (int kh = 0; kh < 3; kh++)
          #pragma unroll
          for (int kw = 0; kw < 3; kw++)
            #pragma unroll
            for (int dj = 0; dj < 8; dj++)
              acc[oi][kh*3+kw] += pv[dj]*xv[kh][dj+kw];
      }
    }
    {
      float xv[3][12];
      #pragma unroll
      for (int q = 0; q < 12; q++){
        bool ok = (56 + q) < 64;
        xv[0][q] = ok ? planes[s0][56+q][c] : 0.f;
        xv[1][q] = ok ? planes[s1][56+q][c] : 0.f;
        xv[2][q] = ok ? planes[s2g][56+q][c] : 0.f;
      }
      #pragma unroll
      for (int oi = 0; oi < 4; oi++){
        float4 pa = *(const float4*)&plds[w*4+oi][56];
        float4 pbq = *(const float4*)&plds[w*4+oi][60];
        float pv[8] = {pa.x,pa.y,pa.z,pa.w,pbq.x,pbq.y,pbq.z,pbq.w};
        #pragma unroll
        for (int kh = 0; kh < 3; kh++)
          #pragma unroll
          for (int kw = 0; kw < 3; kw++)
            #pragma unroll
            for (int dj = 0; dj < 8; dj++)
              acc[oi][kh*3+kw] += pv[dj]*xv[kh][dj+kw];
      }
    }
    __syncthreads();
  }
  #pragma unroll
  for (int oi = 0; oi < 4; oi++){
    float* Gr = G + (size_t)(o0 + w*4 + oi)*CKn + lane*9;
    #pragma unroll
    for (int q = 0; q < 9; q++) atomicAdd(&Gr[q], acc[oi][q]);
  }
}

__global__ __launch_bounds__(576) void k_final_old(const float* __restrict__ w, const float* __restrict__ G,
                                                   const float* __restrict__ S1, const float* __restrict__ S2,
                                                   float* __restrict__ dw){
  int o = blockIdx.x; int k = threadIdx.x;
  float s1 = S1[o]; if (s1 == 0.f) s1 = 1.f;
  dw[o*CKn + k] = (G[o*CKn + k] - S2[o]*w[o*CKn + k]) / s1;
}

extern "C" void kernel_launch(void* const* d_in, const int* in_sizes, int n_in,
                              void* d_out, int out_size, void* d_ws, size_t ws_size,
                              hipStream_t stream){
  const float* x    = (const float*)d_in[0];
  const float* w    = (const float*)d_in[1];
  const float* bias = (const float*)d_in[2];
  float* y  = (float*)d_out;
  float* dw = (float*)d_out + Y_ELEMS;
  float* ws = (float*)d_ws;

  if (ws_size >= WS_NEED){
    float* S1 = ws + NS1;
    float* S2 = ws + NS2;
    float* G  = ws + NG;
    ushort16* wnb = (ushort16*)(ws + NWNB);
    ushort16* xb  = (ushort16*)(ws + NXB);
    ushort16* pb  = (ushort16*)(ws + NPB);
    k_norm  <<<dim3(On),      dim3(256), 0, stream>>>(w, wnb, S1, S2, G, KSB);
    k_xb    <<<dim3(8192),    dim3(256), 0, stream>>>(x, xb);
    k_convm <<<dim3(31, Bn),  dim3(256), 0, stream>>>(x, wnb, bias, y);
    k_softp <<<dim3(Bn, 31),  dim3(256), 0, stream>>>(y, pb, S1, S2);
    k_deltam<<<dim3(32, 16),  dim3(512), 0, stream>>>(xb, pb, G);
    k_finalm<<<dim3(On),      dim3(CKn), 0, stream>>>(w, G, S1, S2, dw);
  } else {
    float* S1   = ws + 73728;
    float* S2   = ws + 73856;
    float* G    = ws + 73984;
    float* mbuf = ws + 147712;
    float* invd = ws + 270720;
    ushort16* wnb = (ushort16*)(ws + 393728);
    k_norm     <<<dim3(On),      dim3(256), 0, stream>>>(w, wnb, S1, S2, G, 1);
    k_convm    <<<dim3(31, Bn),  dim3(256), 0, stream>>>(x, wnb, bias, y);
    k_soft_old <<<dim3(Bn, 16),  dim3(256), 0, stream>>>(y, mbuf, invd, S1, S2);
    k_delta_old<<<dim3(8, Bn*4), dim3(256), 0, stream>>>(x, y, mbuf, invd, G);
    k_final_old<<<dim3(On),      dim3(CKn), 0, stream>>>(w, G, S1, S2, dw);
  }
}

// Round 4
// 263.166 us; speedup vs baseline: 1.2661x; 1.2661x over previous
//
#include <hip/hip_runtime.h>

#define Bn 32
#define Cn 64
#define Hn 64
#define Wn 64
#define On 128
#define HP 62
#define WP 62
#define CKn 576
#define Ln (HP*WP)          // 3844
#define Y_ELEMS (Bn*On*Ln)  // 15745024

typedef unsigned int uint32;
typedef unsigned short ushort16;
typedef __bf16 bf16x8 __attribute__((ext_vector_type(8)));
typedef float floatx4 __attribute__((ext_vector_type(4)));

static __device__ __forceinline__ uint32 bf16r(float f){
  uint32 u = __float_as_uint(f);
  return (u + 0x7FFFu + ((u >> 16) & 1u)) >> 16;
}

// ---------------- new-path ws layout (floats) ----------------
#define KSB   4
#define GSZ   (On*CKn)            // 73728
#define NS1   0
#define NS2   128
#define NG    256                 // KSB * GSZ floats = 294912
#define NWNB  (NG + KSB*GSZ)      // 295168
#define NXB   (NWNB + 36864)      // 332032
#define NPB   (NXB + 4194304)     // 4526336  (proven-safe layout)
#define WS_NEED ((size_t)49800000)

__global__ __launch_bounds__(256) void k_norm(const float* __restrict__ w, ushort16* __restrict__ wnb,
                                              float* __restrict__ S1, float* __restrict__ S2,
                                              float* __restrict__ G, int ngbuf){
  int o = blockIdx.x; int t = threadIdx.x;
  for (int kq = 0; kq < ngbuf; kq++)
    for (int k = t; k < CKn; k += 256) G[(size_t)kq*GSZ + o*CKn + k] = 0.f;
  if (t == 0){ S1[o] = 0.f; S2[o] = 0.f; }
  float s = 0.f;
  for (int k = t; k < CKn; k += 256){ float v = w[o*CKn + k]; s += v*v; }
  #pragma unroll
  for (int off = 32; off; off >>= 1) s += __shfl_down(s, off);
  __shared__ float red[4]; __shared__ float sh_inv;
  if ((t & 63) == 0) red[t >> 6] = s;
  __syncthreads();
  if (t == 0){
    float tot = red[0] + red[1] + red[2] + red[3];
    float nrm = sqrtf(tot);
    sh_inv = (nrm == 0.f) ? 1.f : 1.f/nrm;
  }
  __syncthreads();
  float inv = sh_inv;
  for (int k = t; k < CKn; k += 256){
    float v = w[o*CKn + k] * inv;
    int c = k / 9;
    int q = k - c*9;
    wnb[o*CKn + q*64 + c] = (ushort16)bf16r(v);
  }
}

// x fp32 -> bf16, layout unchanged [b][c][h][w]
__global__ __launch_bounds__(256) void k_xb(const float* __restrict__ x, ushort16* __restrict__ xb){
  size_t idx = ((size_t)blockIdx.x*256 + threadIdx.x)*4;
  float4 v = *(const float4*)(x + idx);
  uint2 o;
  o.x = bf16r(v.x) | (bf16r(v.y) << 16);
  o.y = bf16r(v.z) | (bf16r(v.w) << 16);
  *(uint2*)(xb + idx) = o;
}

// MFMA implicit-GEMM conv (unchanged).
__global__ __launch_bounds__(256, 3) void k_convm(const float* __restrict__ x,
                                                  const ushort16* __restrict__ wnb,
                                                  const float* __restrict__ bias,
                                                  float* __restrict__ y){
  __shared__ ushort16 slab[4*64*68];
  __shared__ ushort16 Bl[2][128*36];
  int t = threadIdx.x;
  int lane = t & 63;
  int wv = t >> 6;
  int mtile = blockIdx.x;
  int b = blockIdx.y;
  int i0 = mtile*2;
  {
    int c0 = (t & 31)*2;
    int grp = t >> 5;
    int r = grp >> 1;
    int w0 = (grp & 1)*32;
    const float* p0 = x + (((size_t)b*Cn + c0)*Hn + (i0 + r))*Wn + w0;
    const float* p1 = p0 + (size_t)Hn*Wn;
    #pragma unroll
    for (int ch = 0; ch < 4; ch++){
      float4 A0 = *(const float4*)(p0 + ch*8);
      float4 A1 = *(const float4*)(p0 + ch*8 + 4);
      float4 B0 = *(const float4*)(p1 + ch*8);
      float4 B1 = *(const float4*)(p1 + ch*8 + 4);
      float v0[8] = {A0.x,A0.y,A0.z,A0.w,A1.x,A1.y,A1.z,A1.w};
      float v1[8] = {B0.x,B0.y,B0.z,B0.w,B1.x,B1.y,B1.z,B1.w};
      #pragma unroll
      for (int qq = 0; qq < 8; qq++){
        int wloc = w0 + ch*8 + qq;
        *(uint32*)&slab[(r*64 + wloc)*68 + c0] = (bf16r(v1[qq]) << 16) | bf16r(v0[qq]);
      }
    }
  }
  int ob = t >> 1;
  int kh16 = (t & 1)*16;
  const ushort16* wrow = wnb + (size_t)ob*CKn + kh16;
  {
    uint4 bA = *(const uint4*)(wrow);
    uint4 bB = *(const uint4*)(wrow + 8);
    ushort16* dst = &Bl[0][ob*36 + kh16];
    ((uint2*)dst)[0] = make_uint2(bA.x, bA.y);
    ((uint2*)dst)[1] = make_uint2(bA.z, bA.w);
    ((uint2*)dst)[2] = make_uint2(bB.x, bB.y);
    ((uint2*)dst)[3] = make_uint2(bB.z, bB.w);
  }
  int quad8 = (lane >> 4) << 3;
  int iT[2], jT[2];
  #pragma unroll
  for (int mt = 0; mt < 2; mt++){
    int m = wv*32 + mt*16 + (lane & 15);
    int pos = m < 124 ? m : 123;
    int hi = pos >= 62;
    iT[mt] = hi;
    jT[mt] = pos - (hi ? 62 : 0);
  }
  floatx4 acc[2][8];
  #pragma unroll
  for (int mt = 0; mt < 2; mt++)
    #pragma unroll
    for (int nt = 0; nt < 8; nt++)
      acc[mt][nt] = (floatx4){0.f, 0.f, 0.f, 0.f};
  union U8 { uint2 u[2]; bf16x8 v; };
  for (int s = 0; s < 18; s++){
    uint4 nA, nB;
    if (s < 17){
      nA = *(const uint4*)(wrow + (s+1)*32);
      nB = *(const uint4*)(wrow + (s+1)*32 + 8);
    }
    __syncthreads();
    int k0 = s*32 + quad8;
    int q = k0 >> 6;
    int c0 = k0 & 63;
    int kh = (q*86) >> 8;
    int kw = q - kh*3;
    bf16x8 af[2];
    #pragma unroll
    for (int mt = 0; mt < 2; mt++){
      const ushort16* ap = &slab[((iT[mt] + kh)*64 + jT[mt] + kw)*68 + c0];
      U8 ua;
      ua.u[0] = *(const uint2*)(ap);
      ua.u[1] = *(const uint2*)(ap + 4);
      af[mt] = ua.v;
    }
    const ushort16* bbase = &Bl[s & 1][(lane & 15)*36 + quad8];
    bf16x8 bf[8];
    #pragma unroll
    for (int nt = 0; nt < 8; nt++){
      const ushort16* bp = bbase + nt*576;
      U8 ub;
      ub.u[0] = *(const uint2*)(bp);
      ub.u[1] = *(const uint2*)(bp + 4);
      bf[nt] = ub.v;
    }
    #pragma unroll
    for (int mt = 0; mt < 2; mt++)
      #pragma unroll
      for (int nt = 0; nt < 8; nt++)
        acc[mt][nt] = __builtin_amdgcn_mfma_f32_16x16x32_bf16(af[mt], bf[nt], acc[mt][nt], 0, 0, 0);
    if (s < 17){
      ushort16* dst = &Bl[(s+1) & 1][ob*36 + kh16];
      ((uint2*)dst)[0] = make_uint2(nA.x, nA.y);
      ((uint2*)dst)[1] = make_uint2(nA.z, nA.w);
      ((uint2*)dst)[2] = make_uint2(nB.x, nB.y);
      ((uint2*)dst)[3] = make_uint2(nB.z, nB.w);
    }
  }
  float bv[8];
  #pragma unroll
  for (int nt = 0; nt < 8; nt++) bv[nt] = bias[nt*16 + (lane & 15)];
  #pragma unroll
  for (int mt = 0; mt < 2; mt++){
    #pragma unroll
    for (int reg = 0; reg < 4; reg++){
      int m = wv*32 + mt*16 + (lane >> 4)*4 + reg;
      if (m < 124){
        int hi = m >= 62;
        int ii = i0 + hi;
        int jj = m - (hi ? 62 : 0);
        float* yp = y + (((size_t)b*On)*HP + ii)*WP + jj;
        #pragma unroll
        for (int nt = 0; nt < 8; nt++){
          int o = nt*16 + (lane & 15);
          yp[(size_t)o*Ln] = acc[mt][nt][reg] + bv[nt];
        }
      }
    }
  }
}

// softmax v2 (unchanged)
__global__ __launch_bounds__(256) void k_softp(const float* __restrict__ y, ushort16* __restrict__ pb,
                                               float* __restrict__ S1, float* __restrict__ S2){
  __shared__ float mpart[2][256], dpart[2][256];
  __shared__ float s1loc[128], s2loc[128];
  int b = blockIdx.x;
  int s = blockIdx.y;          // 0..30
  int i0 = s*2;
  int t = threadIdx.x;
  int j = t & 63;
  int og = t >> 6;
  if (t < 128){ s1loc[t] = 0.f; s2loc[t] = 0.f; }
  int je = j < WP ? j : (WP-1);
  const float* yb = y + ((size_t)b*On)*Ln + (size_t)i0*WP + je;
  // pass 1
  float m0 = -3.0e38f, m1 = -3.0e38f, d0 = 0.f, d1 = 0.f;
  for (int oi = 0; oi < 32; oi++){
    int o = og*32 + oi;
    const float* yp = yb + (size_t)o*Ln;
    float v0 = yp[0];
    float v1 = yp[WP];
    float n0 = fmaxf(m0, v0);
    d0 = d0*__expf(m0 - n0) + __expf(v0 - n0);
    m0 = n0;
    float n1 = fmaxf(m1, v1);
    d1 = d1*__expf(m1 - n1) + __expf(v1 - n1);
    m1 = n1;
  }
  mpart[0][t] = m0; dpart[0][t] = d0;
  mpart[1][t] = m1; dpart[1][t] = d1;
  __syncthreads();
  float mc[2], ic[2];
  #pragma unroll
  for (int r = 0; r < 2; r++){
    float ma = mpart[r][j],      mb = mpart[r][64+j];
    float mcc = mpart[r][128+j], md = mpart[r][192+j];
    float mm = fmaxf(fmaxf(ma, mb), fmaxf(mcc, md));
    float dd = dpart[r][j]*__expf(ma-mm) + dpart[r][64+j]*__expf(mb-mm)
             + dpart[r][128+j]*__expf(mcc-mm) + dpart[r][192+j]*__expf(md-mm);
    mc[r] = mm; ic[r] = 1.f/dd;
  }
  // pass 2
  bool act = j < WP;
  for (int oi = 0; oi < 32; oi++){
    int o = og*32 + oi;
    const float* yp = yb + (size_t)o*Ln;
    float r0 = 0.f, r1 = 0.f;
    if (act){
      r0 = __expf(yp[0] - mc[0]) * ic[0];
      r1 = __expf(yp[WP] - mc[1]) * ic[1];
    }
    float p0 = r0*r0, p1 = r1*r1;
    ushort16* pp = pb + (((size_t)b*On + o)*HP + i0)*64 + j;
    pp[0]  = (ushort16)bf16r(p0);
    pp[64] = (ushort16)bf16r(p1);
    float s1v = r0 + r1, s2v = p0 + p1;
    #pragma unroll
    for (int off = 32; off; off >>= 1){ s1v += __shfl_down(s1v, off); s2v += __shfl_down(s2v, off); }
    if (j == 0){ s1loc[o] += s1v; s2loc[o] += s2v; }   // single writer per o per block
  }
  __syncthreads();
  if (t < 128){ atomicAdd(&S1[t], s1loc[t]); atomicAdd(&S2[t], s2loc[t]); }
}

// MFMA delta v5: LDS-staged tiled GEMM.
// R2/R3 post-mortem: two different schedules, identical 126us, VGPR=40, all
// pipes <9% -> bottleneck is the 16-way per-instruction row-scatter of every
// global load (16 cache lines / instr, nothing coalesces). Fix = canonical
// structure: coalesced global -> LDS tiles -> ds_read fragments.
// Block 512 thr = 8 waves = (4 o-groups x 2 i-halves); grid (ntk=4, b=32, oh=2)
// = 256 blocks = 1/CU. Per i-iter stage: P-tile 2set x 64o x 64pos (granule
// XOR-swizzle for bank-even b128 A-reads) + x-tile 2set x 16c x 3kh x 72
// (144B rows naturally bank-even; tail elements 64..71 zeroed once, multiplied
// only by P=0 padding). Single LDS buffer, 2 barriers/iter, next-iter global
// loads issued into regs before compute barrier (latency hides under compute).
// Epilogue: ih-pair LDS reduce -> 2.36M global atomics (R0-proven), 8-way
// contention via 4 G stripes by (b&3).
#define DOKH2(av, dc, ec, off) { \
  U16 f0, f1, f2; \
  f0.q = dc; \
  f1.q = make_uint4((dc.x>>16)|(dc.y<<16), (dc.y>>16)|(dc.z<<16), \
                    (dc.z>>16)|(dc.w<<16), (dc.w>>16)|(ec<<16)); \
  f2.q = make_uint4(dc.y, dc.z, dc.w, ec); \
  acc[(off)+0] = __builtin_amdgcn_mfma_f32_16x16x32_bf16(av, f0.v, acc[(off)+0], 0, 0, 0); \
  acc[(off)+1] = __builtin_amdgcn_mfma_f32_16x16x32_bf16(av, f1.v, acc[(off)+1], 0, 0, 0); \
  acc[(off)+2] = __builtin_amdgcn_mfma_f32_16x16x32_bf16(av, f2.v, acc[(off)+2], 0, 0, 0); \
}

__global__ __launch_bounds__(512, 2) void k_deltam(const ushort16* __restrict__ xb,
                                                   const ushort16* __restrict__ pb,
                                                   float* __restrict__ G){
  // LDS: pt 2set*64*128B = 16384B | xt 2set*48 rows*144B = 13824B | scratch 36864B (reused)
  __shared__ uint4 lds4[36864/16];
  char* ldsb = (char*)lds4;
  int t = threadIdx.x;
  int lane = t & 63;
  int wv = t >> 6;          // 0..7
  int mgl = wv & 3;         // o-subgroup within oh-half
  int ih  = wv >> 2;        // i-half handled by this wave
  int ntk = blockIdx.x;     // 0..3 channel-quarter
  int b   = blockIdx.y;
  int oh  = blockIdx.z;     // 0..1 o-half
  int cl = lane & 15;
  int quad = lane >> 4;
  int quad8 = quad << 3;

  // ---- staging thread roles (fixed across iters) ----
  // P: thread t -> row o128 = t>>2 (0..127): set sP=o128>>6, o=o128&63, seg=t&3
  int o128 = t >> 2;
  int sP = o128 >> 6;
  int oP = o128 & 63;
  int segP = t & 3;
  const ushort16* pbase = pb + ((size_t)b*On + oh*64 + oP)*(HP*64) + segP*16;
  int pIrow = sP*31;        // + it
  char* pwr = ldsb + (sP*64 + oP)*128;
  int psw0 = ((2*segP)     ^ (oP & 7)) << 4;
  int psw1 = ((2*segP + 1) ^ (oP & 7)) << 4;
  // x: unit1 row r1 = t>>3 (0..63), part p = t&7 ; unit2 (t<256): r2 = 64+(t>>3)
  int pX = t & 7;
  int r1 = t >> 3;
  int s1_ = (r1 >= 48) ? 1 : 0;
  int rr1 = r1 - s1_*48;
  int c1 = rr1/3, kh1 = rr1 - c1*3;
  int r2 = 64 + (t >> 3);             // only t<256
  int rr2 = r2 - 48;                  // set 1
  int c2 = rr2/3, kh2 = rr2 - c2*3;
  const ushort16* xbb = xb + ((size_t)b*Cn + ntk*16)*(Hn*Wn) + pX*8;
  const ushort16* x1base = xbb + (size_t)c1*(Hn*Wn);
  const ushort16* x2base = xbb + (size_t)c2*(Hn*Wn);
  int x1Irow = s1_*31 + kh1;          // + it
  int x2Irow = 31 + kh2;              // + it
  char* x1wr = ldsb + 16384 + (s1_*48 + c1*3 + kh1)*144 + pX*16;
  char* x2wr = ldsb + 16384 + (48    + c2*3 + kh2)*144 + pX*16;

  // zero x-tile tails once (elements 64..71 of each of 96 rows)
  if (t < 96) *(uint4*)(ldsb + 16384 + t*144 + 128) = make_uint4(0,0,0,0);

  // ---- compute-side bases ----
  const char* ptb = ldsb + ih*8192;
  const char* xtb = ldsb + 16384 + ih*6912;
  int orow = mgl*16 + cl;   // row within set (o&7 == cl&7 since mgl*16 % 8 == 0)
  int o7 = cl & 7;

  floatx4 acc[9];
  #pragma unroll
  for (int nt = 0; nt < 9; nt++) acc[nt] = (floatx4){0.f, 0.f, 0.f, 0.f};
  union U16 { uint4 q; bf16x8 v; };

  // prologue: load iter 0 into regs
  uint4 pr0, pr1, xr0, xr1;
  {
    const ushort16* prow = pbase + (size_t)(pIrow + 0)*64;
    pr0 = *(const uint4*)(prow);
    pr1 = *(const uint4*)(prow + 8);
    xr0 = *(const uint4*)(x1base + (size_t)(x1Irow + 0)*Wn);
    if (t < 256) xr1 = *(const uint4*)(x2base + (size_t)(x2Irow + 0)*Wn);
  }

  for (int it = 0; it < 31; ++it){
    __syncthreads();                 // previous compute done reading LDS
    // store staged regs -> LDS
    *(uint4*)(pwr + psw0) = pr0;
    *(uint4*)(pwr + psw1) = pr1;
    *(uint4*)(x1wr) = xr0;
    if (t < 256) *(uint4*)(x2wr) = xr1;
    // issue next iter's global loads (land during compute)
    if (it < 30){
      const ushort16* prow = pbase + (size_t)(pIrow + it + 1)*64;
      pr0 = *(const uint4*)(prow);
      pr1 = *(const uint4*)(prow + 8);
      xr0 = *(const uint4*)(x1base + (size_t)(x1Irow + it + 1)*Wn);
      if (t < 256) xr1 = *(const uint4*)(x2base + (size_t)(x2Irow + it + 1)*Wn);
    }
    __syncthreads();                 // tile ready
    // compute: 2 slices x 3 kh x 3 kw = 18 MFMA
    #pragma unroll
    for (int sl = 0; sl < 2; sl++){
      U16 a;
      a.q = *(const uint4*)(ptb + orow*128 + (((sl*4 + quad) ^ o7) << 4));
      #pragma unroll
      for (int kh = 0; kh < 3; kh++){
        const char* rb = xtb + (cl*3 + kh)*144;
        uint4 d = *(const uint4*)(rb + ((sl*32 + quad8) << 1));
        uint32 e = *(const uint32*)(rb + ((sl*32 + quad8 + 8) << 1));
        DOKH2(a.v, d, e, kh*3)
      }
    }
  }

  // ---- epilogue: reduce ih-pairs in LDS, one atomic per element ----
  __syncthreads();
  float* sc = (float*)ldsb;          // 4*16*144 floats = 9216 (36864B)
  if (ih == 1){
    #pragma unroll
    for (int nt = 0; nt < 9; nt++)
      #pragma unroll
      for (int reg = 0; reg < 4; reg++)
        sc[(mgl*16 + quad*4 + reg)*144 + nt*16 + cl] = acc[nt][reg];
  }
  __syncthreads();
  if (ih == 0){
    float* Gq = G + (size_t)(b & 3)*GSZ;
    #pragma unroll
    for (int nt = 0; nt < 9; nt++)
      #pragma unroll
      for (int reg = 0; reg < 4; reg++){
        int ol = mgl*16 + quad*4 + reg;
        int og = oh*64 + ol;
        float v = acc[nt][reg] + sc[ol*144 + nt*16 + cl];
        atomicAdd(&Gq[(size_t)og*CKn + nt*64 + ntk*16 + cl], v);
      }
  }
}

__global__ __launch_bounds__(576) void k_finalm(const float* __restrict__ w, const float* __restrict__ G,
                                                const float* __restrict__ S1, const float* __restrict__ S2,
                                                float* __restrict__ dw){
  int o = blockIdx.x; int k = threadIdx.x;
  int c = k / 9;
  int q = k - c*9;
  float s1 = S1[o]; if (s1 == 0.f) s1 = 1.f;
  float g = 0.f;
  #pragma unroll
  for (int kq = 0; kq < KSB; kq++) g += G[(size_t)kq*GSZ + o*CKn + q*64 + c];
  dw[o*CKn + k] = (g - S2[o]*w[o*CKn + k]) / s1;
}

// ---------------- old fallback path ----------------
__global__ __launch_bounds__(256) void k_soft_old(const float* __restrict__ y, float* __restrict__ mbuf,
                                                  float* __restrict__ invdbuf, float* __restrict__ S1,
                                                  float* __restrict__ S2){
  __shared__ float s1loc[128], s2loc[128];
  int t = threadIdx.x;
  if (t < 128){ s1loc[t] = 0.f; s2loc[t] = 0.f; }
  __syncthreads();
  int b = blockIdx.x;
  int i = blockIdx.y*4 + (t >> 6);
  int j = t & 63;
  bool act = (i < 62) && (j < 62);
  const float* yp = y + (((size_t)b*On)*HP + (i < 62 ? i : 0))*WP + j;
  float mx = -3.0e38f;
  if (act){ for (int o = 0; o < On; o++) mx = fmaxf(mx, yp[(size_t)o*Ln]); }
  float den = 0.f;
  if (act){ for (int o = 0; o < On; o++) den += __expf(yp[(size_t)o*Ln] - mx); }
  float inv = act ? 1.f/den : 0.f;
  if (act){
    int pos = (b*HP + i)*WP + j;
    mbuf[pos] = mx; invdbuf[pos] = inv;
  }
  for (int o = 0; o < On; o++){
    float r = act ? __expf(yp[(size_t)o*Ln] - mx)*inv : 0.f;
    float s1v = r, s2v = r*r;
    #pragma unroll
    for (int off = 32; off; off >>= 1){ s1v += __shfl_down(s1v, off); s2v += __shfl_down(s2v, off); }
    if ((t & 63) == 0){ atomicAdd(&s1loc[o], s1v); atomicAdd(&s2loc[o], s2v); }
  }
  __syncthreads();
  if (t < 128){ atomicAdd(&S1[t], s1loc[t]); atomicAdd(&S2[t], s2loc[t]); }
}

__global__ __launch_bounds__(256) void k_delta_old(const float* __restrict__ x, const float* __restrict__ y,
                                                   const float* __restrict__ mbuf, const float* __restrict__ invdbuf,
                                                   float* __restrict__ G){
  __shared__ float planes[3][64][64];
  __shared__ float plds[16][64];
  int o0 = blockIdx.x * 16;
  int bs = blockIdx.y;
  int b = bs >> 2;
  int s = bs & 3;
  int i0 = s * 16;
  int nrows = (s == 3) ? 14 : 16;
  int t = threadIdx.x;
  int lane = t & 63;
  int w = t >> 6;
  int lc = t >> 2;
  int lw0 = (t & 3) << 4;
  const float* xb = x + (size_t)b*(Cn*Hn*Wn) + (size_t)lc*(Hn*Wn) + lw0;
  float acc[4][9];
  #pragma unroll
  for (int oi = 0; oi < 4; oi++)
    #pragma unroll
    for (int q = 0; q < 9; q++) acc[oi][q] = 0.f;
  #pragma unroll
  for (int pp = 0; pp < 2; pp++){
    int ih = i0 + pp;
    const float* src = xb + (size_t)ih*Wn;
    #pragma unroll
    for (int q = 0; q < 16; q++) planes[ih % 3][lw0 + q][lc] = src[q];
  }
  for (int ii = 0; ii < nrows; ii++){
    int i = i0 + ii;
    {
      int ih = i + 2;
      const float* src = xb + (size_t)ih*Wn;
      #pragma unroll
      for (int q = 0; q < 16; q++) planes[ih % 3][lw0 + q][lc] = src[q];
    }
    int R = b*HP + i;
    #pragma unroll
    for (int oi = 0; oi < 4; oi++){
      int o = o0 + w*4 + oi;
      float p = 0.f;
      if (lane < WP){
        int pos = R*WP + lane;
        float yv = y[(((size_t)b*On + o)*HP + i)*WP + lane];
        float r = __expf(yv - mbuf[pos]) * invdbuf[pos];
        p = r*r;
      }
      plds[w*4 + oi][lane] = p;
    }
    __syncthreads();
    int c = lane;
    int s0 = i % 3, s1 = (i+1) % 3, s2g = (i+2) % 3;
    #pragma unroll 1
    for (int jj0 = 0; jj0 < 56; jj0 += 8){
      float xv[3][12];
      #pragma unroll
      for (int q = 0; q < 12; q++){
        xv[0][q] = planes[s0][jj0+q][c];
        xv[1][q] = planes[s1][jj0+q][c];
        xv[2][q] = planes[s2g][jj0+q][c];
      }
      #pragma unroll
      for (int oi = 0; oi < 4; oi++){
        float4 pa = *(const float4*)&plds[w*4+oi][jj0];
        float4 pbq = *(const float4*)&plds[w*4+oi][jj0+4];
        float pv[8] = {pa.x,pa.y,pa.z,pa.w,pbq.x,pbq.y,pbq.z,pbq.w};
        #pragma unroll
        for (int kh = 0; kh < 3; kh++)
          #pragma unroll
          for (int kw = 0; kw < 3; kw++)
            #pragma unroll
            for (int dj = 0; dj < 8; dj++)
              acc[oi][kh*3+kw] += pv[dj]*xv[kh][dj+kw];
      }
    }
    {
      float xv[3][12];
      #pragma unroll
      for (int q = 0; q < 12; q++){
        bool ok = (56 + q) < 64;
        xv[0][q] = ok ? planes[s0][56+q][c] : 0.f;
        xv[1][q] = ok ? planes[s1][56+q][c] : 0.f;
        xv[2][q] = ok ? planes[s2g][56+q][c] : 0.f;
      }
      #pragma unroll
      for (int oi = 0; oi < 4; oi++){
        float4 pa = *(const float4*)&plds[w*4+oi][56];
        float4 pbq = *(const float4*)&plds[w*4+oi][60];
        float pv[8] = {pa.x,pa.y,pa.z,pa.w,pbq.x,pbq.y,pbq.z,pbq.w};
        #pragma unroll
        for (int kh = 0; kh < 3; kh++)
          #pragma unroll
          for (int kw = 0; kw < 3; kw++)
            #pragma unroll
            for (int dj = 0; dj < 8; dj++)
              acc[oi][kh*3+kw] += pv[dj]*xv[kh][dj+kw];
      }
    }
    __syncthreads();
  }
  #pragma unroll
  for (int oi = 0; oi < 4; oi++){
    float* Gr = G + (size_t)(o0 + w*4 + oi)*CKn + lane*9;
    #pragma unroll
    for (int q = 0; q < 9; q++) atomicAdd(&Gr[q], acc[oi][q]);
  }
}

__global__ __launch_bounds__(576) void k_final_old(const float* __restrict__ w, const float* __restrict__ G,
                                                   const float* __restrict__ S1, const float* __restrict__ S2,
                                                   float* __restrict__ dw){
  int o = blockIdx.x; int k = threadIdx.x;
  float s1 = S1[o]; if (s1 == 0.f) s1 = 1.f;
  dw[o*CKn + k] = (G[o*CKn + k] - S2[o]*w[o*CKn + k]) / s1;
}

extern "C" void kernel_launch(void* const* d_in, const int* in_sizes, int n_in,
                              void* d_out, int out_size, void* d_ws, size_t ws_size,
                              hipStream_t stream){
  const float* x    = (const float*)d_in[0];
  const float* w    = (const float*)d_in[1];
  const float* bias = (const float*)d_in[2];
  float* y  = (float*)d_out;
  float* dw = (float*)d_out + Y_ELEMS;
  float* ws = (float*)d_ws;

  if (ws_size >= WS_NEED){
    float* S1 = ws + NS1;
    float* S2 = ws + NS2;
    float* G  = ws + NG;
    ushort16* wnb = (ushort16*)(ws + NWNB);
    ushort16* xb  = (ushort16*)(ws + NXB);
    ushort16* pb  = (ushort16*)(ws + NPB);
    k_norm  <<<dim3(On),      dim3(256), 0, stream>>>(w, wnb, S1, S2, G, KSB);
    k_xb    <<<dim3(8192),    dim3(256), 0, stream>>>(x, xb);
    k_convm <<<dim3(31, Bn),  dim3(256), 0, stream>>>(x, wnb, bias, y);
    k_softp <<<dim3(Bn, 31),  dim3(256), 0, stream>>>(y, pb, S1, S2);
    k_deltam<<<dim3(4, Bn, 2), dim3(512), 0, stream>>>(xb, pb, G);
    k_finalm<<<dim3(On),      dim3(CKn), 0, stream>>>(w, G, S1, S2, dw);
  } else {
    float* S1   = ws + 73728;
    float* S2   = ws + 73856;
    float* G    = ws + 73984;
    float* mbuf = ws + 147712;
    float* invd = ws + 270720;
    ushort16* wnb = (ushort16*)(ws + 393728);
    k_norm     <<<dim3(On),      dim3(256), 0, stream>>>(w, wnb, S1, S2, G, 1);
    k_convm    <<<dim3(31, Bn),  dim3(256), 0, stream>>>(x, wnb, bias, y);
    k_soft_old <<<dim3(Bn, 16),  dim3(256), 0, stream>>>(y, mbuf, invd, S1, S2);
    k_delta_old<<<dim3(8, Bn*4), dim3(256), 0, stream>>>(x, y, mbuf, invd, G);
    k_final_old<<<dim3(On),      dim3(CKn), 0, stream>>>(w, G, S1, S2, dw);
  }
}

// Round 5
// 237.903 us; speedup vs baseline: 1.4005x; 1.1062x over previous
//
#include <hip/hip_runtime.h>

#define Bn 32
#define Cn 64
#define Hn 64
#define Wn 64
#define On 128
#define HP 62
#define WP 62
#define CKn 576
#define Ln (HP*WP)          // 3844
#define Y_ELEMS (Bn*On*Ln)  // 15745024

typedef unsigned int uint32;
typedef unsigned short ushort16;
typedef __bf16 bf16x8 __attribute__((ext_vector_type(8)));
typedef float floatx4 __attribute__((ext_vector_type(4)));

static __device__ __forceinline__ uint32 bf16r(float f){
  uint32 u = __float_as_uint(f);
  return (u + 0x7FFFu + ((u >> 16) & 1u)) >> 16;
}

// ---------------- new-path ws layout (floats) ----------------
#define KSB   4
#define GSZ   (On*CKn)            // 73728
#define NS1   0
#define NS2   128
#define NG    256                 // KSB * GSZ floats = 294912
#define NWNB  (NG + KSB*GSZ)      // 295168
#define NXB   (NWNB + 36864)      // 332032
#define NPB   (NXB + 4194304)     // 4526336  (proven-safe layout)
#define WS_NEED ((size_t)49800000)

__global__ __launch_bounds__(256) void k_norm(const float* __restrict__ w, ushort16* __restrict__ wnb,
                                              float* __restrict__ S1, float* __restrict__ S2,
                                              float* __restrict__ G, int ngbuf){
  int o = blockIdx.x; int t = threadIdx.x;
  for (int kq = 0; kq < ngbuf; kq++)
    for (int k = t; k < CKn; k += 256) G[(size_t)kq*GSZ + o*CKn + k] = 0.f;
  if (t == 0){ S1[o] = 0.f; S2[o] = 0.f; }
  float s = 0.f;
  for (int k = t; k < CKn; k += 256){ float v = w[o*CKn + k]; s += v*v; }
  #pragma unroll
  for (int off = 32; off; off >>= 1) s += __shfl_down(s, off);
  __shared__ float red[4]; __shared__ float sh_inv;
  if ((t & 63) == 0) red[t >> 6] = s;
  __syncthreads();
  if (t == 0){
    float tot = red[0] + red[1] + red[2] + red[3];
    float nrm = sqrtf(tot);
    sh_inv = (nrm == 0.f) ? 1.f : 1.f/nrm;
  }
  __syncthreads();
  float inv = sh_inv;
  for (int k = t; k < CKn; k += 256){
    float v = w[o*CKn + k] * inv;
    int c = k / 9;
    int q = k - c*9;
    wnb[o*CKn + q*64 + c] = (ushort16)bf16r(v);
  }
}

// x fp32 -> bf16, layout unchanged [b][c][h][w]
__global__ __launch_bounds__(256) void k_xb(const float* __restrict__ x, ushort16* __restrict__ xb){
  size_t idx = ((size_t)blockIdx.x*256 + threadIdx.x)*4;
  float4 v = *(const float4*)(x + idx);
  uint2 o;
  o.x = bf16r(v.x) | (bf16r(v.y) << 16);
  o.y = bf16r(v.z) | (bf16r(v.w) << 16);
  *(uint2*)(xb + idx) = o;
}

// MFMA implicit-GEMM conv, v2 epilogue.
// R4 post-mortem: cold-replay WRITE_SIZE = 192 MB vs 63 MB of y (3x write
// amplification); epilogue scattered 64 dwords/thread at o-stride 15376B ->
// ~64 lines touched per wave-store, ~16x sector traffic, ~26us of the 74us.
// Fix: LDS-transpose epilogue. Overlay a 64x130 float tile on slab (33.3KB <=
// 34.8KB), stage fragments (+bias) per o-half, then each wave writes one o's
// 124-float contiguous region as lane-consecutive float2 (fully coalesced,
// full lines). Compute loop untouched.
__global__ __launch_bounds__(256, 3) void k_convm(const float* __restrict__ x,
                                                  const ushort16* __restrict__ wnb,
                                                  const float* __restrict__ bias,
                                                  float* __restrict__ y){
  __shared__ ushort16 slab[4*64*68];
  __shared__ ushort16 Bl[2][128*36];
  int t = threadIdx.x;
  int lane = t & 63;
  int wv = t >> 6;
  int mtile = blockIdx.x;
  int b = blockIdx.y;
  int i0 = mtile*2;
  {
    int c0 = (t & 31)*2;
    int grp = t >> 5;
    int r = grp >> 1;
    int w0 = (grp & 1)*32;
    const float* p0 = x + (((size_t)b*Cn + c0)*Hn + (i0 + r))*Wn + w0;
    const float* p1 = p0 + (size_t)Hn*Wn;
    #pragma unroll
    for (int ch = 0; ch < 4; ch++){
      float4 A0 = *(const float4*)(p0 + ch*8);
      float4 A1 = *(const float4*)(p0 + ch*8 + 4);
      float4 B0 = *(const float4*)(p1 + ch*8);
      float4 B1 = *(const float4*)(p1 + ch*8 + 4);
      float v0[8] = {A0.x,A0.y,A0.z,A0.w,A1.x,A1.y,A1.z,A1.w};
      float v1[8] = {B0.x,B0.y,B0.z,B0.w,B1.x,B1.y,B1.z,B1.w};
      #pragma unroll
      for (int qq = 0; qq < 8; qq++){
        int wloc = w0 + ch*8 + qq;
        *(uint32*)&slab[(r*64 + wloc)*68 + c0] = (bf16r(v1[qq]) << 16) | bf16r(v0[qq]);
      }
    }
  }
  int ob = t >> 1;
  int kh16 = (t & 1)*16;
  const ushort16* wrow = wnb + (size_t)ob*CKn + kh16;
  {
    uint4 bA = *(const uint4*)(wrow);
    uint4 bB = *(const uint4*)(wrow + 8);
    ushort16* dst = &Bl[0][ob*36 + kh16];
    ((uint2*)dst)[0] = make_uint2(bA.x, bA.y);
    ((uint2*)dst)[1] = make_uint2(bA.z, bA.w);
    ((uint2*)dst)[2] = make_uint2(bB.x, bB.y);
    ((uint2*)dst)[3] = make_uint2(bB.z, bB.w);
  }
  int quad8 = (lane >> 4) << 3;
  int iT[2], jT[2];
  #pragma unroll
  for (int mt = 0; mt < 2; mt++){
    int m = wv*32 + mt*16 + (lane & 15);
    int pos = m < 124 ? m : 123;
    int hi = pos >= 62;
    iT[mt] = hi;
    jT[mt] = pos - (hi ? 62 : 0);
  }
  floatx4 acc[2][8];
  #pragma unroll
  for (int mt = 0; mt < 2; mt++)
    #pragma unroll
    for (int nt = 0; nt < 8; nt++)
      acc[mt][nt] = (floatx4){0.f, 0.f, 0.f, 0.f};
  union U8 { uint2 u[2]; bf16x8 v; };
  for (int s = 0; s < 18; s++){
    uint4 nA, nB;
    if (s < 17){
      nA = *(const uint4*)(wrow + (s+1)*32);
      nB = *(const uint4*)(wrow + (s+1)*32 + 8);
    }
    __syncthreads();
    int k0 = s*32 + quad8;
    int q = k0 >> 6;
    int c0 = k0 & 63;
    int kh = (q*86) >> 8;
    int kw = q - kh*3;
    bf16x8 af[2];
    #pragma unroll
    for (int mt = 0; mt < 2; mt++){
      const ushort16* ap = &slab[((iT[mt] + kh)*64 + jT[mt] + kw)*68 + c0];
      U8 ua;
      ua.u[0] = *(const uint2*)(ap);
      ua.u[1] = *(const uint2*)(ap + 4);
      af[mt] = ua.v;
    }
    const ushort16* bbase = &Bl[s & 1][(lane & 15)*36 + quad8];
    bf16x8 bf[8];
    #pragma unroll
    for (int nt = 0; nt < 8; nt++){
      const ushort16* bp = bbase + nt*576;
      U8 ub;
      ub.u[0] = *(const uint2*)(bp);
      ub.u[1] = *(const uint2*)(bp + 4);
      bf[nt] = ub.v;
    }
    #pragma unroll
    for (int mt = 0; mt < 2; mt++)
      #pragma unroll
      for (int nt = 0; nt < 8; nt++)
        acc[mt][nt] = __builtin_amdgcn_mfma_f32_16x16x32_bf16(af[mt], bf[nt], acc[mt][nt], 0, 0, 0);
    if (s < 17){
      ushort16* dst = &Bl[(s+1) & 1][ob*36 + kh16];
      ((uint2*)dst)[0] = make_uint2(nA.x, nA.y);
      ((uint2*)dst)[1] = make_uint2(nA.z, nA.w);
      ((uint2*)dst)[2] = make_uint2(nB.x, nB.y);
      ((uint2*)dst)[3] = make_uint2(nB.z, nB.w);
    }
  }
  float bv[8];
  #pragma unroll
  for (int nt = 0; nt < 8; nt++) bv[nt] = bias[nt*16 + (lane & 15)];
  // ---- coalesced epilogue via LDS transpose ----
  float* ytile = (float*)slab;            // 64 x 130 floats = 33280 B (slab is 34816 B)
  int cl = lane & 15;
  int quad = lane >> 4;
  #pragma unroll
  for (int chunk = 0; chunk < 2; chunk++){
    __syncthreads();                      // slab free (last MFMA reads / prev chunk stores done)
    #pragma unroll
    for (int nt4 = 0; nt4 < 4; nt4++){
      int nt = chunk*4 + nt4;
      int ol = nt4*16 + cl;
      #pragma unroll
      for (int mt = 0; mt < 2; mt++){
        #pragma unroll
        for (int reg = 0; reg < 4; reg++){
          int m = wv*32 + mt*16 + quad*4 + reg;
          if (m < 124) ytile[ol*130 + m] = acc[mt][nt][reg] + bv[nt];
        }
      }
    }
    __syncthreads();
    // each wave writes one o's 124 contiguous floats as lane-consecutive float2
    #pragma unroll
    for (int r = 0; r < 16; r++){
      int ol = wv*16 + r;
      int o = chunk*64 + ol;
      if (lane < 62){
        float2 v = *(float2*)&ytile[ol*130 + lane*2];
        *(float2*)&y[((size_t)b*On + o)*Ln + (size_t)i0*WP + lane*2] = v;
      }
    }
  }
}

// softmax v2 (unchanged)
__global__ __launch_bounds__(256) void k_softp(const float* __restrict__ y, ushort16* __restrict__ pb,
                                               float* __restrict__ S1, float* __restrict__ S2){
  __shared__ float mpart[2][256], dpart[2][256];
  __shared__ float s1loc[128], s2loc[128];
  int b = blockIdx.x;
  int s = blockIdx.y;          // 0..30
  int i0 = s*2;
  int t = threadIdx.x;
  int j = t & 63;
  int og = t >> 6;
  if (t < 128){ s1loc[t] = 0.f; s2loc[t] = 0.f; }
  int je = j < WP ? j : (WP-1);
  const float* yb = y + ((size_t)b*On)*Ln + (size_t)i0*WP + je;
  // pass 1
  float m0 = -3.0e38f, m1 = -3.0e38f, d0 = 0.f, d1 = 0.f;
  for (int oi = 0; oi < 32; oi++){
    int o = og*32 + oi;
    const float* yp = yb + (size_t)o*Ln;
    float v0 = yp[0];
    float v1 = yp[WP];
    float n0 = fmaxf(m0, v0);
    d0 = d0*__expf(m0 - n0) + __expf(v0 - n0);
    m0 = n0;
    float n1 = fmaxf(m1, v1);
    d1 = d1*__expf(m1 - n1) + __expf(v1 - n1);
    m1 = n1;
  }
  mpart[0][t] = m0; dpart[0][t] = d0;
  mpart[1][t] = m1; dpart[1][t] = d1;
  __syncthreads();
  float mc[2], ic[2];
  #pragma unroll
  for (int r = 0; r < 2; r++){
    float ma = mpart[r][j],      mb = mpart[r][64+j];
    float mcc = mpart[r][128+j], md = mpart[r][192+j];
    float mm = fmaxf(fmaxf(ma, mb), fmaxf(mcc, md));
    float dd = dpart[r][j]*__expf(ma-mm) + dpart[r][64+j]*__expf(mb-mm)
             + dpart[r][128+j]*__expf(mcc-mm) + dpart[r][192+j]*__expf(md-mm);
    mc[r] = mm; ic[r] = 1.f/dd;
  }
  // pass 2
  bool act = j < WP;
  for (int oi = 0; oi < 32; oi++){
    int o = og*32 + oi;
    const float* yp = yb + (size_t)o*Ln;
    float r0 = 0.f, r1 = 0.f;
    if (act){
      r0 = __expf(yp[0] - mc[0]) * ic[0];
      r1 = __expf(yp[WP] - mc[1]) * ic[1];
    }
    float p0 = r0*r0, p1 = r1*r1;
    ushort16* pp = pb + (((size_t)b*On + o)*HP + i0)*64 + j;
    pp[0]  = (ushort16)bf16r(p0);
    pp[64] = (ushort16)bf16r(p1);
    float s1v = r0 + r1, s2v = p0 + p1;
    #pragma unroll
    for (int off = 32; off; off >>= 1){ s1v += __shfl_down(s1v, off); s2v += __shfl_down(s2v, off); }
    if (j == 0){ s1loc[o] += s1v; s2loc[o] += s2v; }   // single writer per o per block
  }
  __syncthreads();
  if (t < 128){ atomicAdd(&S1[t], s1loc[t]); atomicAdd(&S2[t], s2loc[t]); }
}

// MFMA delta v5: LDS-staged tiled GEMM (unchanged; R4 win).
#define DOKH2(av, dc, ec, off) { \
  U16 f0, f1, f2; \
  f0.q = dc; \
  f1.q = make_uint4((dc.x>>16)|(dc.y<<16), (dc.y>>16)|(dc.z<<16), \
                    (dc.z>>16)|(dc.w<<16), (dc.w>>16)|(ec<<16)); \
  f2.q = make_uint4(dc.y, dc.z, dc.w, ec); \
  acc[(off)+0] = __builtin_amdgcn_mfma_f32_16x16x32_bf16(av, f0.v, acc[(off)+0], 0, 0, 0); \
  acc[(off)+1] = __builtin_amdgcn_mfma_f32_16x16x32_bf16(av, f1.v, acc[(off)+1], 0, 0, 0); \
  acc[(off)+2] = __builtin_amdgcn_mfma_f32_16x16x32_bf16(av, f2.v, acc[(off)+2], 0, 0, 0); \
}

__global__ __launch_bounds__(512, 2) void k_deltam(const ushort16* __restrict__ xb,
                                                   const ushort16* __restrict__ pb,
                                                   float* __restrict__ G){
  // LDS: pt 2set*64*128B = 16384B | xt 2set*48 rows*144B = 13824B | scratch 36864B (reused)
  __shared__ uint4 lds4[36864/16];
  char* ldsb = (char*)lds4;
  int t = threadIdx.x;
  int lane = t & 63;
  int wv = t >> 6;          // 0..7
  int mgl = wv & 3;         // o-subgroup within oh-half
  int ih  = wv >> 2;        // i-half handled by this wave
  int ntk = blockIdx.x;     // 0..3 channel-quarter
  int b   = blockIdx.y;
  int oh  = blockIdx.z;     // 0..1 o-half
  int cl = lane & 15;
  int quad = lane >> 4;
  int quad8 = quad << 3;

  // ---- staging thread roles (fixed across iters) ----
  int o128 = t >> 2;
  int sP = o128 >> 6;
  int oP = o128 & 63;
  int segP = t & 3;
  const ushort16* pbase = pb + ((size_t)b*On + oh*64 + oP)*(HP*64) + segP*16;
  int pIrow = sP*31;        // + it
  char* pwr = ldsb + (sP*64 + oP)*128;
  int psw0 = ((2*segP)     ^ (oP & 7)) << 4;
  int psw1 = ((2*segP + 1) ^ (oP & 7)) << 4;
  int pX = t & 7;
  int r1 = t >> 3;
  int s1_ = (r1 >= 48) ? 1 : 0;
  int rr1 = r1 - s1_*48;
  int c1 = rr1/3, kh1 = rr1 - c1*3;
  int rr2 = (64 + (t >> 3)) - 48;     // set 1 (only t<256)
  int c2 = rr2/3, kh2 = rr2 - c2*3;
  const ushort16* xbb = xb + ((size_t)b*Cn + ntk*16)*(Hn*Wn) + pX*8;
  const ushort16* x1base = xbb + (size_t)c1*(Hn*Wn);
  const ushort16* x2base = xbb + (size_t)c2*(Hn*Wn);
  int x1Irow = s1_*31 + kh1;          // + it
  int x2Irow = 31 + kh2;              // + it
  char* x1wr = ldsb + 16384 + (s1_*48 + c1*3 + kh1)*144 + pX*16;
  char* x2wr = ldsb + 16384 + (48    + c2*3 + kh2)*144 + pX*16;

  if (t < 96) *(uint4*)(ldsb + 16384 + t*144 + 128) = make_uint4(0,0,0,0);

  const char* ptb = ldsb + ih*8192;
  const char* xtb = ldsb + 16384 + ih*6912;
  int orow = mgl*16 + cl;
  int o7 = cl & 7;

  floatx4 acc[9];
  #pragma unroll
  for (int nt = 0; nt < 9; nt++) acc[nt] = (floatx4){0.f, 0.f, 0.f, 0.f};
  union U16 { uint4 q; bf16x8 v; };

  uint4 pr0, pr1, xr0, xr1;
  {
    const ushort16* prow = pbase + (size_t)(pIrow + 0)*64;
    pr0 = *(const uint4*)(prow);
    pr1 = *(const uint4*)(prow + 8);
    xr0 = *(const uint4*)(x1base + (size_t)(x1Irow + 0)*Wn);
    if (t < 256) xr1 = *(const uint4*)(x2base + (size_t)(x2Irow + 0)*Wn);
  }

  for (int it = 0; it < 31; ++it){
    __syncthreads();
    *(uint4*)(pwr + psw0) = pr0;
    *(uint4*)(pwr + psw1) = pr1;
    *(uint4*)(x1wr) = xr0;
    if (t < 256) *(uint4*)(x2wr) = xr1;
    if (it < 30){
      const ushort16* prow = pbase + (size_t)(pIrow + it + 1)*64;
      pr0 = *(const uint4*)(prow);
      pr1 = *(const uint4*)(prow + 8);
      xr0 = *(const uint4*)(x1base + (size_t)(x1Irow + it + 1)*Wn);
      if (t < 256) xr1 = *(const uint4*)(x2base + (size_t)(x2Irow + it + 1)*Wn);
    }
    __syncthreads();
    #pragma unroll
    for (int sl = 0; sl < 2; sl++){
      U16 a;
      a.q = *(const uint4*)(ptb + orow*128 + (((sl*4 + quad) ^ o7) << 4));
      #pragma unroll
      for (int kh = 0; kh < 3; kh++){
        const char* rb = xtb + (cl*3 + kh)*144;
        uint4 d = *(const uint4*)(rb + ((sl*32 + quad8) << 1));
        uint32 e = *(const uint32*)(rb + ((sl*32 + quad8 + 8) << 1));
        DOKH2(a.v, d, e, kh*3)
      }
    }
  }

  __syncthreads();
  float* sc = (float*)ldsb;
  if (ih == 1){
    #pragma unroll
    for (int nt = 0; nt < 9; nt++)
      #pragma unroll
      for (int reg = 0; reg < 4; reg++)
        sc[(mgl*16 + quad*4 + reg)*144 + nt*16 + cl] = acc[nt][reg];
  }
  __syncthreads();
  if (ih == 0){
    float* Gq = G + (size_t)(b & 3)*GSZ;
    #pragma unroll
    for (int nt = 0; nt < 9; nt++)
      #pragma unroll
      for (int reg = 0; reg < 4; reg++){
        int ol = mgl*16 + quad*4 + reg;
        int og = oh*64 + ol;
        float v = acc[nt][reg] + sc[ol*144 + nt*16 + cl];
        atomicAdd(&Gq[(size_t)og*CKn + nt*64 + ntk*16 + cl], v);
      }
  }
}

__global__ __launch_bounds__(576) void k_finalm(const float* __restrict__ w, const float* __restrict__ G,
                                                const float* __restrict__ S1, const float* __restrict__ S2,
                                                float* __restrict__ dw){
  int o = blockIdx.x; int k = threadIdx.x;
  int c = k / 9;
  int q = k - c*9;
  float s1 = S1[o]; if (s1 == 0.f) s1 = 1.f;
  float g = 0.f;
  #pragma unroll
  for (int kq = 0; kq < KSB; kq++) g += G[(size_t)kq*GSZ + o*CKn + q*64 + c];
  dw[o*CKn + k] = (g - S2[o]*w[o*CKn + k]) / s1;
}

// ---------------- old fallback path ----------------
__global__ __launch_bounds__(256) void k_soft_old(const float* __restrict__ y, float* __restrict__ mbuf,
                                                  float* __restrict__ invdbuf, float* __restrict__ S1,
                                                  float* __restrict__ S2){
  __shared__ float s1loc[128], s2loc[128];
  int t = threadIdx.x;
  if (t < 128){ s1loc[t] = 0.f; s2loc[t] = 0.f; }
  __syncthreads();
  int b = blockIdx.x;
  int i = blockIdx.y*4 + (t >> 6);
  int j = t & 63;
  bool act = (i < 62) && (j < 62);
  const float* yp = y + (((size_t)b*On)*HP + (i < 62 ? i : 0))*WP + j;
  float mx = -3.0e38f;
  if (act){ for (int o = 0; o < On; o++) mx = fmaxf(mx, yp[(size_t)o*Ln]); }
  float den = 0.f;
  if (act){ for (int o = 0; o < On; o++) den += __expf(yp[(size_t)o*Ln] - mx); }
  float inv = act ? 1.f/den : 0.f;
  if (act){
    int pos = (b*HP + i)*WP + j;
    mbuf[pos] = mx; invdbuf[pos] = inv;
  }
  for (int o = 0; o < On; o++){
    float r = act ? __expf(yp[(size_t)o*Ln] - mx)*inv : 0.f;
    float s1v = r, s2v = r*r;
    #pragma unroll
    for (int off = 32; off; off >>= 1){ s1v += __shfl_down(s1v, off); s2v += __shfl_down(s2v, off); }
    if ((t & 63) == 0){ atomicAdd(&s1loc[o], s1v); atomicAdd(&s2loc[o], s2v); }
  }
  __syncthreads();
  if (t < 128){ atomicAdd(&S1[t], s1loc[t]); atomicAdd(&S2[t], s2loc[t]); }
}

__global__ __launch_bounds__(256) void k_delta_old(const float* __restrict__ x, const float* __restrict__ y,
                                                   const float* __restrict__ mbuf, const float* __restrict__ invdbuf,
                                                   float* __restrict__ G){
  __shared__ float planes[3][64][64];
  __shared__ float plds[16][64];
  int o0 = blockIdx.x * 16;
  int bs = blockIdx.y;
  int b = bs >> 2;
  int s = bs & 3;
  int i0 = s * 16;
  int nrows = (s == 3) ? 14 : 16;
  int t = threadIdx.x;
  int lane = t & 63;
  int w = t >> 6;
  int lc = t >> 2;
  int lw0 = (t & 3) << 4;
  const float* xb = x + (size_t)b*(Cn*Hn*Wn) + (size_t)lc*(Hn*Wn) + lw0;
  float acc[4][9];
  #pragma unroll
  for (int oi = 0; oi < 4; oi++)
    #pragma unroll
    for (int q = 0; q < 9; q++) acc[oi][q] = 0.f;
  #pragma unroll
  for (int pp = 0; pp < 2; pp++){
    int ih = i0 + pp;
    const float* src = xb + (size_t)ih*Wn;
    #pragma unroll
    for (int q = 0; q < 16; q++) planes[ih % 3][lw0 + q][lc] = src[q];
  }
  for (int ii = 0; ii < nrows; ii++){
    int i = i0 + ii;
    {
      int ih = i + 2;
      const float* src = xb + (size_t)ih*Wn;
      #pragma unroll
      for (int q = 0; q < 16; q++) planes[ih % 3][lw0 + q][lc] = src[q];
    }
    int R = b*HP + i;
    #pragma unroll
    for (int oi = 0; oi < 4; oi++){
      int o = o0 + w*4 + oi;
      float p = 0.f;
      if (lane < WP){
        int pos = R*WP + lane;
        float yv = y[(((size_t)b*On + o)*HP + i)*WP + lane];
        float r = __expf(yv - mbuf[pos]) * invdbuf[pos];
        p = r*r;
      }
      plds[w*4 + oi][lane] = p;
    }
    __syncthreads();
    int c = lane;
    int s0 = i % 3, s1 = (i+1) % 3, s2g = (i+2) % 3;
    #pragma unroll 1
    for (int jj0 = 0; jj0 < 56; jj0 += 8){
      float xv[3][12];
      #pragma unroll
      for (int q = 0; q < 12; q++){
        xv[0][q] = planes[s0][jj0+q][c];
        xv[1][q] = planes[s1][jj0+q][c];
        xv[2][q] = planes[s2g][jj0+q][c];
      }
      #pragma unroll
      for (int oi = 0; oi < 4; oi++){
        float4 pa = *(const float4*)&plds[w*4+oi][jj0];
        float4 pbq = *(const float4*)&plds[w*4+oi][jj0+4];
        float pv[8] = {pa.x,pa.y,pa.z,pa.w,pbq.x,pbq.y,pbq.z,pbq.w};
        #pragma unroll
        for (int kh = 0; kh < 3; kh++)
          #pragma unroll
          for (int kw = 0; kw < 3; kw++)
            #pragma unroll
            for (int dj = 0; dj < 8; dj++)
              acc[oi][kh*3+kw] += pv[dj]*xv[kh][dj+kw];
      }
    }
    {
      float xv[3][12];
      #pragma unroll
      for (int q = 0; q < 12; q++){
        bool ok = (56 + q) < 64;
        xv[0][q] = ok ? planes[s0][56+q][c] : 0.f;
        xv[1][q] = ok ? planes[s1][56+q][c] : 0.f;
        xv[2][q] = ok ? planes[s2g][56+q][c] : 0.f;
      }
      #pragma unroll
      for (int oi = 0; oi < 4; oi++){
        float4 pa = *(const float4*)&plds[w*4+oi][56];
        float4 pbq = *(const float4*)&plds[w*4+oi][60];
        float pv[8] = {pa.x,pa.y,pa.z,pa.w,pbq.x,pbq.y,pbq.z,pbq.w};
        #pragma unroll
        for (int kh = 0; kh < 3; kh++)
          #pragma unroll
          for (int kw = 0; kw < 3; kw++)
            #pragma unroll
            for (int dj = 0; dj < 8; dj++)
              acc[oi][kh*3+kw] += pv[dj]*xv[kh][dj+kw];
      }
    }
    __syncthreads();
  }
  #pragma unroll
  for (int oi = 0; oi < 4; oi++){
    float* Gr = G + (size_t)(o0 + w*4 + oi)*CKn + lane*9;
    #pragma unroll
    for (int q = 0; q < 9; q++) atomicAdd(&Gr[q], acc[oi][q]);
  }
}

__global__ __launch_bounds__(576) void k_final_old(const float* __restrict__ w, const float* __restrict__ G,
                                                   const float* __restrict__ S1, const float* __restrict__ S2,
                                                   float* __restrict__ dw){
  int o = blockIdx.x; int k = threadIdx.x;
  float s1 = S1[o]; if (s1 == 0.f) s1 = 1.f;
  dw[o*CKn + k] = (G[o*CKn + k] - S2[o]*w[o*CKn + k]) / s1;
}

extern "C" void kernel_launch(void* const* d_in, const int* in_sizes, int n_in,
                              void* d_out, int out_size, void* d_ws, size_t ws_size,
                              hipStream_t stream){
  const float* x    = (const float*)d_in[0];
  const float* w    = (const float*)d_in[1];
  const float* bias = (const float*)d_in[2];
  float* y  = (float*)d_out;
  float* dw = (float*)d_out + Y_ELEMS;
  float* ws = (float*)d_ws;

  if (ws_size >= WS_NEED){
    float* S1 = ws + NS1;
    float* S2 = ws + NS2;
    float* G  = ws + NG;
    ushort16* wnb = (ushort16*)(ws + NWNB);
    ushort16* xb  = (ushort16*)(ws + NXB);
    ushort16* pb  = (ushort16*)(ws + NPB);
    k_norm  <<<dim3(On),      dim3(256), 0, stream>>>(w, wnb, S1, S2, G, KSB);
    k_xb    <<<dim3(8192),    dim3(256), 0, stream>>>(x, xb);
    k_convm <<<dim3(31, Bn),  dim3(256), 0, stream>>>(x, wnb, bias, y);
    k_softp <<<dim3(Bn, 31),  dim3(256), 0, stream>>>(y, pb, S1, S2);
    k_deltam<<<dim3(4, Bn, 2), dim3(512), 0, stream>>>(xb, pb, G);
    k_finalm<<<dim3(On),      dim3(CKn), 0, stream>>>(w, G, S1, S2, dw);
  } else {
    float* S1   = ws + 73728;
    float* S2   = ws + 73856;
    float* G    = ws + 73984;
    float* mbuf = ws + 147712;
    float* invd = ws + 270720;
    ushort16* wnb = (ushort16*)(ws + 393728);
    k_norm     <<<dim3(On),      dim3(256), 0, stream>>>(w, wnb, S1, S2, G, 1);
    k_convm    <<<dim3(31, Bn),  dim3(256), 0, stream>>>(x, wnb, bias, y);
    k_soft_old <<<dim3(Bn, 16),  dim3(256), 0, stream>>>(y, mbuf, invd, S1, S2);
    k_delta_old<<<dim3(8, Bn*4), dim3(256), 0, stream>>>(x, y, mbuf, invd, G);
    k_final_old<<<dim3(On),      dim3(CKn), 0, stream>>>(w, G, S1, S2, dw);
  }
}

// Round 6
// 226.350 us; speedup vs baseline: 1.4720x; 1.0510x over previous
//
#include <hip/hip_runtime.h>

#define Bn 32
#define Cn 64
#define Hn 64
#define Wn 64
#define On 128
#define HP 62
#define WP 62
#define CKn 576
#define Ln (HP*WP)          // 3844
#define Y_ELEMS (Bn*On*Ln)  // 15745024

typedef unsigned int uint32;
typedef unsigned short ushort16;
typedef __bf16 bf16x8 __attribute__((ext_vector_type(8)));
typedef float floatx4 __attribute__((ext_vector_type(4)));

static __device__ __forceinline__ uint32 bf16r(float f){
  uint32 u = __float_as_uint(f);
  return (u + 0x7FFFu + ((u >> 16) & 1u)) >> 16;
}

// ---------------- new-path ws layout (floats) ----------------
#define KSB   4
#define GSZ   (On*CKn)            // 73728
#define NS1   0
#define NS2   128
#define NG    256                 // KSB * GSZ floats = 294912
#define NWNB  (NG + KSB*GSZ)      // 295168
#define NXB   (NWNB + 36864)      // 332032
#define NPB   (NXB + 4194304)     // 4526336  (proven-safe layout)
#define WS_NEED ((size_t)49800000)

__global__ __launch_bounds__(256) void k_norm(const float* __restrict__ w, ushort16* __restrict__ wnb,
                                              float* __restrict__ S1, float* __restrict__ S2,
                                              float* __restrict__ G, int ngbuf){
  int o = blockIdx.x; int t = threadIdx.x;
  for (int kq = 0; kq < ngbuf; kq++)
    for (int k = t; k < CKn; k += 256) G[(size_t)kq*GSZ + o*CKn + k] = 0.f;
  if (t == 0){ S1[o] = 0.f; S2[o] = 0.f; }
  float s = 0.f;
  for (int k = t; k < CKn; k += 256){ float v = w[o*CKn + k]; s += v*v; }
  #pragma unroll
  for (int off = 32; off; off >>= 1) s += __shfl_down(s, off);
  __shared__ float red[4]; __shared__ float sh_inv;
  if ((t & 63) == 0) red[t >> 6] = s;
  __syncthreads();
  if (t == 0){
    float tot = red[0] + red[1] + red[2] + red[3];
    float nrm = sqrtf(tot);
    sh_inv = (nrm == 0.f) ? 1.f : 1.f/nrm;
  }
  __syncthreads();
  float inv = sh_inv;
  for (int k = t; k < CKn; k += 256){
    float v = w[o*CKn + k] * inv;
    int c = k / 9;
    int q = k - c*9;
    wnb[o*CKn + q*64 + c] = (ushort16)bf16r(v);
  }
}

// x fp32 -> bf16, layout unchanged [b][c][h][w]
__global__ __launch_bounds__(256) void k_xb(const float* __restrict__ x, ushort16* __restrict__ xb){
  size_t idx = ((size_t)blockIdx.x*256 + threadIdx.x)*4;
  float4 v = *(const float4*)(x + idx);
  uint2 o;
  o.x = bf16r(v.x) | (bf16r(v.y) << 16);
  o.y = bf16r(v.z) | (bf16r(v.w) << 16);
  *(uint2*)(xb + idx) = o;
}

// MFMA implicit-GEMM conv with coalesced LDS-transpose epilogue (R5 win).
__global__ __launch_bounds__(256, 3) void k_convm(const float* __restrict__ x,
                                                  const ushort16* __restrict__ wnb,
                                                  const float* __restrict__ bias,
                                                  float* __restrict__ y){
  __shared__ ushort16 slab[4*64*68];
  __shared__ ushort16 Bl[2][128*36];
  int t = threadIdx.x;
  int lane = t & 63;
  int wv = t >> 6;
  int mtile = blockIdx.x;
  int b = blockIdx.y;
  int i0 = mtile*2;
  {
    int c0 = (t & 31)*2;
    int grp = t >> 5;
    int r = grp >> 1;
    int w0 = (grp & 1)*32;
    const float* p0 = x + (((size_t)b*Cn + c0)*Hn + (i0 + r))*Wn + w0;
    const float* p1 = p0 + (size_t)Hn*Wn;
    #pragma unroll
    for (int ch = 0; ch < 4; ch++){
      float4 A0 = *(const float4*)(p0 + ch*8);
      float4 A1 = *(const float4*)(p0 + ch*8 + 4);
      float4 B0 = *(const float4*)(p1 + ch*8);
      float4 B1 = *(const float4*)(p1 + ch*8 + 4);
      float v0[8] = {A0.x,A0.y,A0.z,A0.w,A1.x,A1.y,A1.z,A1.w};
      float v1[8] = {B0.x,B0.y,B0.z,B0.w,B1.x,B1.y,B1.z,B1.w};
      #pragma unroll
      for (int qq = 0; qq < 8; qq++){
        int wloc = w0 + ch*8 + qq;
        *(uint32*)&slab[(r*64 + wloc)*68 + c0] = (bf16r(v1[qq]) << 16) | bf16r(v0[qq]);
      }
    }
  }
  int ob = t >> 1;
  int kh16 = (t & 1)*16;
  const ushort16* wrow = wnb + (size_t)ob*CKn + kh16;
  {
    uint4 bA = *(const uint4*)(wrow);
    uint4 bB = *(const uint4*)(wrow + 8);
    ushort16* dst = &Bl[0][ob*36 + kh16];
    ((uint2*)dst)[0] = make_uint2(bA.x, bA.y);
    ((uint2*)dst)[1] = make_uint2(bA.z, bA.w);
    ((uint2*)dst)[2] = make_uint2(bB.x, bB.y);
    ((uint2*)dst)[3] = make_uint2(bB.z, bB.w);
  }
  int quad8 = (lane >> 4) << 3;
  int iT[2], jT[2];
  #pragma unroll
  for (int mt = 0; mt < 2; mt++){
    int m = wv*32 + mt*16 + (lane & 15);
    int pos = m < 124 ? m : 123;
    int hi = pos >= 62;
    iT[mt] = hi;
    jT[mt] = pos - (hi ? 62 : 0);
  }
  floatx4 acc[2][8];
  #pragma unroll
  for (int mt = 0; mt < 2; mt++)
    #pragma unroll
    for (int nt = 0; nt < 8; nt++)
      acc[mt][nt] = (floatx4){0.f, 0.f, 0.f, 0.f};
  union U8 { uint2 u[2]; bf16x8 v; };
  for (int s = 0; s < 18; s++){
    uint4 nA, nB;
    if (s < 17){
      nA = *(const uint4*)(wrow + (s+1)*32);
      nB = *(const uint4*)(wrow + (s+1)*32 + 8);
    }
    __syncthreads();
    int k0 = s*32 + quad8;
    int q = k0 >> 6;
    int c0 = k0 & 63;
    int kh = (q*86) >> 8;
    int kw = q - kh*3;
    bf16x8 af[2];
    #pragma unroll
    for (int mt = 0; mt < 2; mt++){
      const ushort16* ap = &slab[((iT[mt] + kh)*64 + jT[mt] + kw)*68 + c0];
      U8 ua;
      ua.u[0] = *(const uint2*)(ap);
      ua.u[1] = *(const uint2*)(ap + 4);
      af[mt] = ua.v;
    }
    const ushort16* bbase = &Bl[s & 1][(lane & 15)*36 + quad8];
    bf16x8 bf[8];
    #pragma unroll
    for (int nt = 0; nt < 8; nt++){
      const ushort16* bp = bbase + nt*576;
      U8 ub;
      ub.u[0] = *(const uint2*)(bp);
      ub.u[1] = *(const uint2*)(bp + 4);
      bf[nt] = ub.v;
    }
    #pragma unroll
    for (int mt = 0; mt < 2; mt++)
      #pragma unroll
      for (int nt = 0; nt < 8; nt++)
        acc[mt][nt] = __builtin_amdgcn_mfma_f32_16x16x32_bf16(af[mt], bf[nt], acc[mt][nt], 0, 0, 0);
    if (s < 17){
      ushort16* dst = &Bl[(s+1) & 1][ob*36 + kh16];
      ((uint2*)dst)[0] = make_uint2(nA.x, nA.y);
      ((uint2*)dst)[1] = make_uint2(nA.z, nA.w);
      ((uint2*)dst)[2] = make_uint2(nB.x, nB.y);
      ((uint2*)dst)[3] = make_uint2(nB.z, nB.w);
    }
  }
  float bv[8];
  #pragma unroll
  for (int nt = 0; nt < 8; nt++) bv[nt] = bias[nt*16 + (lane & 15)];
  // ---- coalesced epilogue via LDS transpose ----
  float* ytile = (float*)slab;            // 64 x 130 floats = 33280 B (slab is 34816 B)
  int cl = lane & 15;
  int quad = lane >> 4;
  #pragma unroll
  for (int chunk = 0; chunk < 2; chunk++){
    __syncthreads();
    #pragma unroll
    for (int nt4 = 0; nt4 < 4; nt4++){
      int nt = chunk*4 + nt4;
      int ol = nt4*16 + cl;
      #pragma unroll
      for (int mt = 0; mt < 2; mt++){
        #pragma unroll
        for (int reg = 0; reg < 4; reg++){
          int m = wv*32 + mt*16 + quad*4 + reg;
          if (m < 124) ytile[ol*130 + m] = acc[mt][nt][reg] + bv[nt];
        }
      }
    }
    __syncthreads();
    #pragma unroll
    for (int r = 0; r < 16; r++){
      int ol = wv*16 + r;
      int o = chunk*64 + ol;
      if (lane < 62){
        float2 v = *(float2*)&ytile[ol*130 + lane*2];
        *(float2*)&y[((size_t)b*On + o)*Ln + (size_t)i0*WP + lane*2] = v;
      }
    }
  }
}

// softmax v3: register-resident y.
// R5 post-mortem: VGPR=16 -> 128 per-thread loads serialized one latency each
// (~34k cyc/block); traffic already minimal. Fix: load all 64 y values (32 o x
// 2 rows) into unrolled register arrays (batched issue, latency paid once),
// compute local max + exp ONCE and keep the exp values; after the og-merge the
// final r is one mul per value (no pass-2 reloads, expf count halved).
__global__ __launch_bounds__(256, 4) void k_softp(const float* __restrict__ y, ushort16* __restrict__ pb,
                                                  float* __restrict__ S1, float* __restrict__ S2){
  __shared__ float mpart[2][256], dpart[2][256];
  __shared__ float s1loc[128], s2loc[128];
  int b = blockIdx.x;
  int s = blockIdx.y;          // 0..30
  int i0 = s*2;
  int t = threadIdx.x;
  int j = t & 63;
  int og = t >> 6;
  if (t < 128){ s1loc[t] = 0.f; s2loc[t] = 0.f; }
  int je = j < WP ? j : (WP-1);
  const float* yb = y + ((size_t)b*On + og*32)*Ln + (size_t)i0*WP + je;
  // batched load: all 32 o's x 2 rows into registers
  float v0[32], v1[32];
  #pragma unroll
  for (int oi = 0; oi < 32; oi++){
    const float* yp = yb + (size_t)oi*Ln;
    v0[oi] = yp[0];
    v1[oi] = yp[WP];
  }
  // local max per row
  float m0 = v0[0], m1 = v1[0];
  #pragma unroll
  for (int oi = 1; oi < 32; oi++){
    m0 = fmaxf(m0, v0[oi]);
    m1 = fmaxf(m1, v1[oi]);
  }
  // exp once, keep values; local denominator
  float d0 = 0.f, d1 = 0.f;
  #pragma unroll
  for (int oi = 0; oi < 32; oi++){
    v0[oi] = __expf(v0[oi] - m0); d0 += v0[oi];
    v1[oi] = __expf(v1[oi] - m1); d1 += v1[oi];
  }
  mpart[0][t] = m0; dpart[0][t] = d0;
  mpart[1][t] = m1; dpart[1][t] = d1;
  __syncthreads();
  // 4-way og merge -> global max + inv-denominator; rescale factor per og
  float scl[2];
  {
    float ml[2] = {m0, m1};
    #pragma unroll
    for (int r = 0; r < 2; r++){
      float ma = mpart[r][j],      mb = mpart[r][64+j];
      float mcc = mpart[r][128+j], md = mpart[r][192+j];
      float mm = fmaxf(fmaxf(ma, mb), fmaxf(mcc, md));
      float dd = dpart[r][j]*__expf(ma-mm) + dpart[r][64+j]*__expf(mb-mm)
               + dpart[r][128+j]*__expf(mcc-mm) + dpart[r][192+j]*__expf(md-mm);
      scl[r] = __expf(ml[r]-mm) / dd;
    }
  }
  bool act = j < WP;
  float sc0 = act ? scl[0] : 0.f;   // inactive lanes contribute 0 and write 0 pads
  float sc1 = act ? scl[1] : 0.f;
  ushort16* ppb = pb + (((size_t)b*On + og*32)*HP + i0)*64 + j;
  #pragma unroll
  for (int oi = 0; oi < 32; oi++){
    float r0 = v0[oi]*sc0;
    float r1 = v1[oi]*sc1;
    float p0 = r0*r0, p1 = r1*r1;
    ushort16* pp = ppb + (size_t)oi*(HP*64);
    pp[0]  = (ushort16)bf16r(p0);
    pp[64] = (ushort16)bf16r(p1);
    float s1v = r0 + r1, s2v = p0 + p1;
    #pragma unroll
    for (int off = 32; off; off >>= 1){ s1v += __shfl_down(s1v, off); s2v += __shfl_down(s2v, off); }
    if (j == 0){ s1loc[og*32 + oi] += s1v; s2loc[og*32 + oi] += s2v; }
  }
  __syncthreads();
  if (t < 128){ atomicAdd(&S1[t], s1loc[t]); atomicAdd(&S2[t], s2loc[t]); }
}

// MFMA delta v5: LDS-staged tiled GEMM (unchanged; R4 win).
#define DOKH2(av, dc, ec, off) { \
  U16 f0, f1, f2; \
  f0.q = dc; \
  f1.q = make_uint4((dc.x>>16)|(dc.y<<16), (dc.y>>16)|(dc.z<<16), \
                    (dc.z>>16)|(dc.w<<16), (dc.w>>16)|(ec<<16)); \
  f2.q = make_uint4(dc.y, dc.z, dc.w, ec); \
  acc[(off)+0] = __builtin_amdgcn_mfma_f32_16x16x32_bf16(av, f0.v, acc[(off)+0], 0, 0, 0); \
  acc[(off)+1] = __builtin_amdgcn_mfma_f32_16x16x32_bf16(av, f1.v, acc[(off)+1], 0, 0, 0); \
  acc[(off)+2] = __builtin_amdgcn_mfma_f32_16x16x32_bf16(av, f2.v, acc[(off)+2], 0, 0, 0); \
}

__global__ __launch_bounds__(512, 2) void k_deltam(const ushort16* __restrict__ xb,
                                                   const ushort16* __restrict__ pb,
                                                   float* __restrict__ G){
  __shared__ uint4 lds4[36864/16];
  char* ldsb = (char*)lds4;
  int t = threadIdx.x;
  int lane = t & 63;
  int wv = t >> 6;          // 0..7
  int mgl = wv & 3;
  int ih  = wv >> 2;
  int ntk = blockIdx.x;
  int b   = blockIdx.y;
  int oh  = blockIdx.z;
  int cl = lane & 15;
  int quad = lane >> 4;
  int quad8 = quad << 3;

  int o128 = t >> 2;
  int sP = o128 >> 6;
  int oP = o128 & 63;
  int segP = t & 3;
  const ushort16* pbase = pb + ((size_t)b*On + oh*64 + oP)*(HP*64) + segP*16;
  int pIrow = sP*31;
  char* pwr = ldsb + (sP*64 + oP)*128;
  int psw0 = ((2*segP)     ^ (oP & 7)) << 4;
  int psw1 = ((2*segP + 1) ^ (oP & 7)) << 4;
  int pX = t & 7;
  int r1 = t >> 3;
  int s1_ = (r1 >= 48) ? 1 : 0;
  int rr1 = r1 - s1_*48;
  int c1 = rr1/3, kh1 = rr1 - c1*3;
  int rr2 = (64 + (t >> 3)) - 48;
  int c2 = rr2/3, kh2 = rr2 - c2*3;
  const ushort16* xbb = xb + ((size_t)b*Cn + ntk*16)*(Hn*Wn) + pX*8;
  const ushort16* x1base = xbb + (size_t)c1*(Hn*Wn);
  const ushort16* x2base = xbb + (size_t)c2*(Hn*Wn);
  int x1Irow = s1_*31 + kh1;
  int x2Irow = 31 + kh2;
  char* x1wr = ldsb + 16384 + (s1_*48 + c1*3 + kh1)*144 + pX*16;
  char* x2wr = ldsb + 16384 + (48    + c2*3 + kh2)*144 + pX*16;

  if (t < 96) *(uint4*)(ldsb + 16384 + t*144 + 128) = make_uint4(0,0,0,0);

  const char* ptb = ldsb + ih*8192;
  const char* xtb = ldsb + 16384 + ih*6912;
  int orow = mgl*16 + cl;
  int o7 = cl & 7;

  floatx4 acc[9];
  #pragma unroll
  for (int nt = 0; nt < 9; nt++) acc[nt] = (floatx4){0.f, 0.f, 0.f, 0.f};
  union U16 { uint4 q; bf16x8 v; };

  uint4 pr0, pr1, xr0, xr1;
  {
    const ushort16* prow = pbase + (size_t)(pIrow + 0)*64;
    pr0 = *(const uint4*)(prow);
    pr1 = *(const uint4*)(prow + 8);
    xr0 = *(const uint4*)(x1base + (size_t)(x1Irow + 0)*Wn);
    if (t < 256) xr1 = *(const uint4*)(x2base + (size_t)(x2Irow + 0)*Wn);
  }

  for (int it = 0; it < 31; ++it){
    __syncthreads();
    *(uint4*)(pwr + psw0) = pr0;
    *(uint4*)(pwr + psw1) = pr1;
    *(uint4*)(x1wr) = xr0;
    if (t < 256) *(uint4*)(x2wr) = xr1;
    if (it < 30){
      const ushort16* prow = pbase + (size_t)(pIrow + it + 1)*64;
      pr0 = *(const uint4*)(prow);
      pr1 = *(const uint4*)(prow + 8);
      xr0 = *(const uint4*)(x1base + (size_t)(x1Irow + it + 1)*Wn);
      if (t < 256) xr1 = *(const uint4*)(x2base + (size_t)(x2Irow + it + 1)*Wn);
    }
    __syncthreads();
    #pragma unroll
    for (int sl = 0; sl < 2; sl++){
      U16 a;
      a.q = *(const uint4*)(ptb + orow*128 + (((sl*4 + quad) ^ o7) << 4));
      #pragma unroll
      for (int kh = 0; kh < 3; kh++){
        const char* rb = xtb + (cl*3 + kh)*144;
        uint4 d = *(const uint4*)(rb + ((sl*32 + quad8) << 1));
        uint32 e = *(const uint32*)(rb + ((sl*32 + quad8 + 8) << 1));
        DOKH2(a.v, d, e, kh*3)
      }
    }
  }

  __syncthreads();
  float* sc = (float*)ldsb;
  if (ih == 1){
    #pragma unroll
    for (int nt = 0; nt < 9; nt++)
      #pragma unroll
      for (int reg = 0; reg < 4; reg++)
        sc[(mgl*16 + quad*4 + reg)*144 + nt*16 + cl] = acc[nt][reg];
  }
  __syncthreads();
  if (ih == 0){
    float* Gq = G + (size_t)(b & 3)*GSZ;
    #pragma unroll
    for (int nt = 0; nt < 9; nt++)
      #pragma unroll
      for (int reg = 0; reg < 4; reg++){
        int ol = mgl*16 + quad*4 + reg;
        int og = oh*64 + ol;
        float v = acc[nt][reg] + sc[ol*144 + nt*16 + cl];
        atomicAdd(&Gq[(size_t)og*CKn + nt*64 + ntk*16 + cl], v);
      }
  }
}

__global__ __launch_bounds__(576) void k_finalm(const float* __restrict__ w, const float* __restrict__ G,
                                                const float* __restrict__ S1, const float* __restrict__ S2,
                                                float* __restrict__ dw){
  int o = blockIdx.x; int k = threadIdx.x;
  int c = k / 9;
  int q = k - c*9;
  float s1 = S1[o]; if (s1 == 0.f) s1 = 1.f;
  float g = 0.f;
  #pragma unroll
  for (int kq = 0; kq < KSB; kq++) g += G[(size_t)kq*GSZ + o*CKn + q*64 + c];
  dw[o*CKn + k] = (g - S2[o]*w[o*CKn + k]) / s1;
}

// ---------------- old fallback path ----------------
__global__ __launch_bounds__(256) void k_soft_old(const float* __restrict__ y, float* __restrict__ mbuf,
                                                  float* __restrict__ invdbuf, float* __restrict__ S1,
                                                  float* __restrict__ S2){
  __shared__ float s1loc[128], s2loc[128];
  int t = threadIdx.x;
  if (t < 128){ s1loc[t] = 0.f; s2loc[t] = 0.f; }
  __syncthreads();
  int b = blockIdx.x;
  int i = blockIdx.y*4 + (t >> 6);
  int j = t & 63;
  bool act = (i < 62) && (j < 62);
  const float* yp = y + (((size_t)b*On)*HP + (i < 62 ? i : 0))*WP + j;
  float mx = -3.0e38f;
  if (act){ for (int o = 0; o < On; o++) mx = fmaxf(mx, yp[(size_t)o*Ln]); }
  float den = 0.f;
  if (act){ for (int o = 0; o < On; o++) den += __expf(yp[(size_t)o*Ln] - mx); }
  float inv = act ? 1.f/den : 0.f;
  if (act){
    int pos = (b*HP + i)*WP + j;
    mbuf[pos] = mx; invdbuf[pos] = inv;
  }
  for (int o = 0; o < On; o++){
    float r = act ? __expf(yp[(size_t)o*Ln] - mx)*inv : 0.f;
    float s1v = r, s2v = r*r;
    #pragma unroll
    for (int off = 32; off; off >>= 1){ s1v += __shfl_down(s1v, off); s2v += __shfl_down(s2v, off); }
    if ((t & 63) == 0){ atomicAdd(&s1loc[o], s1v); atomicAdd(&s2loc[o], s2v); }
  }
  __syncthreads();
  if (t < 128){ atomicAdd(&S1[t], s1loc[t]); atomicAdd(&S2[t], s2loc[t]); }
}

__global__ __launch_bounds__(256) void k_delta_old(const float* __restrict__ x, const float* __restrict__ y,
                                                   const float* __restrict__ mbuf, const float* __restrict__ invdbuf,
                                                   float* __restrict__ G){
  __shared__ float planes[3][64][64];
  __shared__ float plds[16][64];
  int o0 = blockIdx.x * 16;
  int bs = blockIdx.y;
  int b = bs >> 2;
  int s = bs & 3;
  int i0 = s * 16;
  int nrows = (s == 3) ? 14 : 16;
  int t = threadIdx.x;
  int lane = t & 63;
  int w = t >> 6;
  int lc = t >> 2;
  int lw0 = (t & 3) << 4;
  const float* xb = x + (size_t)b*(Cn*Hn*Wn) + (size_t)lc*(Hn*Wn) + lw0;
  float acc[4][9];
  #pragma unroll
  for (int oi = 0; oi < 4; oi++)
    #pragma unroll
    for (int q = 0; q < 9; q++) acc[oi][q] = 0.f;
  #pragma unroll
  for (int pp = 0; pp < 2; pp++){
    int ih = i0 + pp;
    const float* src = xb + (size_t)ih*Wn;
    #pragma unroll
    for (int q = 0; q < 16; q++) planes[ih % 3][lw0 + q][lc] = src[q];
  }
  for (int ii = 0; ii < nrows; ii++){
    int i = i0 + ii;
    {
      int ih = i + 2;
      const float* src = xb + (size_t)ih*Wn;
      #pragma unroll
      for (int q = 0; q < 16; q++) planes[ih % 3][lw0 + q][lc] = src[q];
    }
    int R = b*HP + i;
    #pragma unroll
    for (int oi = 0; oi < 4; oi++){
      int o = o0 + w*4 + oi;
      float p = 0.f;
      if (lane < WP){
        int pos = R*WP + lane;
        float yv = y[(((size_t)b*On + o)*HP + i)*WP + lane];
        float r = __expf(yv - mbuf[pos]) * invdbuf[pos];
        p = r*r;
      }
      plds[w*4 + oi][lane] = p;
    }
    __syncthreads();
    int c = lane;
    int s0 = i % 3, s1 = (i+1) % 3, s2g = (i+2) % 3;
    #pragma unroll 1
    for (int jj0 = 0; jj0 < 56; jj0 += 8){
      float xv[3][12];
      #pragma unroll
      for (int q = 0; q < 12; q++){
        xv[0][q] = planes[s0][jj0+q][c];
        xv[1][q] = planes[s1][jj0+q][c];
        xv[2][q] = planes[s2g][jj0+q][c];
      }
      #pragma unroll
      for (int oi = 0; oi < 4; oi++){
        float4 pa = *(const float4*)&plds[w*4+oi][jj0];
        float4 pbq = *(const float4*)&plds[w*4+oi][jj0+4];
        float pv[8] = {pa.x,pa.y,pa.z,pa.w,pbq.x,pbq.y,pbq.z,pbq.w};
        #pragma unroll
        for (int kh = 0; kh < 3; kh++)
          #pragma unroll
          for (int kw = 0; kw < 3; kw++)
            #pragma unroll
            for (int dj = 0; dj < 8; dj++)
              acc[oi][kh*3+kw] += pv[dj]*xv[kh][dj+kw];
      }
    }
    {
      float xv[3][12];
      #pragma unroll
      for (int q = 0; q < 12; q++){
        bool ok = (56 + q) < 64;
        xv[0][q] = ok ? planes[s0][56+q][c] : 0.f;
        xv[1][q] = ok ? planes[s1][56+q][c] : 0.f;
        xv[2][q] = ok ? planes[s2g][56+q][c] : 0.f;
      }
      #pragma unroll
      for (int oi = 0; oi < 4; oi++){
        float4 pa = *(const float4*)&plds[w*4+oi][56];
        float4 pbq = *(const float4*)&plds[w*4+oi][60];
        float pv[8] = {pa.x,pa.y,pa.z,pa.w,pbq.x,pbq.y,pbq.z,pbq.w};
        #pragma unroll
        for (int kh = 0; kh < 3; kh++)
          #pragma unroll
          for (int kw = 0; kw < 3; kw++)
            #pragma unroll
            for (int dj = 0; dj < 8; dj++)
              acc[oi][kh*3+kw] += pv[dj]*xv[kh][dj+kw];
      }
    }
    __syncthreads();
  }
  #pragma unroll
  for (int oi = 0; oi < 4; oi++){
    float* Gr = G + (size_t)(o0 + w*4 + oi)*CKn + lane*9;
    #pragma unroll
    for (int q = 0; q < 9; q++) atomicAdd(&Gr[q], acc[oi][q]);
  }
}

__global__ __launch_bounds__(576) void k_final_old(const float* __restrict__ w, const float* __restrict__ G,
                                                   const float* __restrict__ S1, const float* __restrict__ S2,
                                                   float* __restrict__ dw){
  int o = blockIdx.x; int k = threadIdx.x;
  float s1 = S1[o]; if (s1 == 0.f) s1 = 1.f;
  dw[o*CKn + k] = (G[o*CKn + k] - S2[o]*w[o*CKn + k]) / s1;
}

extern "C" void kernel_launch(void* const* d_in, const int* in_sizes, int n_in,
                              void* d_out, int out_size, void* d_ws, size_t ws_size,
                              hipStream_t stream){
  const float* x    = (const float*)d_in[0];
  const float* w    = (const float*)d_in[1];
  const float* bias = (const float*)d_in[2];
  float* y  = (float*)d_out;
  float* dw = (float*)d_out + Y_ELEMS;
  float* ws = (float*)d_ws;

  if (ws_size >= WS_NEED){
    float* S1 = ws + NS1;
    float* S2 = ws + NS2;
    float* G  = ws + NG;
    ushort16* wnb = (ushort16*)(ws + NWNB);
    ushort16* xb  = (ushort16*)(ws + NXB);
    ushort16* pb  = (ushort16*)(ws + NPB);
    k_norm  <<<dim3(On),      dim3(256), 0, stream>>>(w, wnb, S1, S2, G, KSB);
    k_xb    <<<dim3(8192),    dim3(256), 0, stream>>>(x, xb);
    k_convm <<<dim3(31, Bn),  dim3(256), 0, stream>>>(x, wnb, bias, y);
    k_softp <<<dim3(Bn, 31),  dim3(256), 0, stream>>>(y, pb, S1, S2);
    k_deltam<<<dim3(4, Bn, 2), dim3(512), 0, stream>>>(xb, pb, G);
    k_finalm<<<dim3(On),      dim3(CKn), 0, stream>>>(w, G, S1, S2, dw);
  } else {
    float* S1   = ws + 73728;
    float* S2   = ws + 73856;
    float* G    = ws + 73984;
    float* mbuf = ws + 147712;
    float* invd = ws + 270720;
    ushort16* wnb = (ushort16*)(ws + 393728);
    k_norm     <<<dim3(On),      dim3(256), 0, stream>>>(w, wnb, S1, S2, G, 1);
    k_convm    <<<dim3(31, Bn),  dim3(256), 0, stream>>>(x, wnb, bias, y);
    k_soft_old <<<dim3(Bn, 16),  dim3(256), 0, stream>>>(y, mbuf, invd, S1, S2);
    k_delta_old<<<dim3(8, Bn*4), dim3(256), 0, stream>>>(x, y, mbuf, invd, G);
    k_final_old<<<dim3(On),      dim3(CKn), 0, stream>>>(w, G, S1, S2, dw);
  }
}

// Round 7
// 224.872 us; speedup vs baseline: 1.4817x; 1.0066x over previous
//
#include <hip/hip_runtime.h>

#define Bn 32
#define Cn 64
#define Hn 64
#define Wn 64
#define On 128
#define HP 62
#define WP 62
#define CKn 576
#define Ln (HP*WP)          // 3844
#define Y_ELEMS (Bn*On*Ln)  // 15745024

typedef unsigned int uint32;
typedef unsigned short ushort16;
typedef __bf16 bf16x8 __attribute__((ext_vector_type(8)));
typedef float floatx4 __attribute__((ext_vector_type(4)));

static __device__ __forceinline__ uint32 bf16r(float f){
  uint32 u = __float_as_uint(f);
  return (u + 0x7FFFu + ((u >> 16) & 1u)) >> 16;
}

// ---------------- new-path ws layout (floats) ----------------
#define KSB   4
#define GSZ   (On*CKn)            // 73728
#define NS1   0
#define NS2   128
#define NG    256                 // KSB * GSZ floats = 294912
#define NWNB  (NG + KSB*GSZ)      // 295168
#define NXB   (NWNB + 36864)      // 332032
#define NPB   (NXB + 4194304)     // 4526336  (proven-safe layout)
#define WS_NEED ((size_t)49800000)

__global__ __launch_bounds__(256) void k_norm(const float* __restrict__ w, ushort16* __restrict__ wnb,
                                              float* __restrict__ S1, float* __restrict__ S2,
                                              float* __restrict__ G, int ngbuf){
  int o = blockIdx.x; int t = threadIdx.x;
  for (int kq = 0; kq < ngbuf; kq++)
    for (int k = t; k < CKn; k += 256) G[(size_t)kq*GSZ + o*CKn + k] = 0.f;
  if (t == 0){ S1[o] = 0.f; S2[o] = 0.f; }
  float s = 0.f;
  for (int k = t; k < CKn; k += 256){ float v = w[o*CKn + k]; s += v*v; }
  #pragma unroll
  for (int off = 32; off; off >>= 1) s += __shfl_down(s, off);
  __shared__ float red[4]; __shared__ float sh_inv;
  if ((t & 63) == 0) red[t >> 6] = s;
  __syncthreads();
  if (t == 0){
    float tot = red[0] + red[1] + red[2] + red[3];
    float nrm = sqrtf(tot);
    sh_inv = (nrm == 0.f) ? 1.f : 1.f/nrm;
  }
  __syncthreads();
  float inv = sh_inv;
  for (int k = t; k < CKn; k += 256){
    float v = w[o*CKn + k] * inv;
    int c = k / 9;
    int q = k - c*9;
    wnb[o*CKn + q*64 + c] = (ushort16)bf16r(v);
  }
}

// x fp32 -> bf16, layout unchanged [b][c][h][w]
__global__ __launch_bounds__(256) void k_xb(const float* __restrict__ x, ushort16* __restrict__ xb){
  size_t idx = ((size_t)blockIdx.x*256 + threadIdx.x)*4;
  float4 v = *(const float4*)(x + idx);
  uint2 o;
  o.x = bf16r(v.x) | (bf16r(v.y) << 16);
  o.y = bf16r(v.z) | (bf16r(v.w) << 16);
  *(uint2*)(xb + idx) = o;
}

// MFMA implicit-GEMM conv with coalesced LDS-transpose epilogue (R5 win).
__global__ __launch_bounds__(256, 3) void k_convm(const float* __restrict__ x,
                                                  const ushort16* __restrict__ wnb,
                                                  const float* __restrict__ bias,
                                                  float* __restrict__ y){
  __shared__ ushort16 slab[4*64*68];
  __shared__ ushort16 Bl[2][128*36];
  int t = threadIdx.x;
  int lane = t & 63;
  int wv = t >> 6;
  int mtile = blockIdx.x;
  int b = blockIdx.y;
  int i0 = mtile*2;
  {
    int c0 = (t & 31)*2;
    int grp = t >> 5;
    int r = grp >> 1;
    int w0 = (grp & 1)*32;
    const float* p0 = x + (((size_t)b*Cn + c0)*Hn + (i0 + r))*Wn + w0;
    const float* p1 = p0 + (size_t)Hn*Wn;
    #pragma unroll
    for (int ch = 0; ch < 4; ch++){
      float4 A0 = *(const float4*)(p0 + ch*8);
      float4 A1 = *(const float4*)(p0 + ch*8 + 4);
      float4 B0 = *(const float4*)(p1 + ch*8);
      float4 B1 = *(const float4*)(p1 + ch*8 + 4);
      float v0[8] = {A0.x,A0.y,A0.z,A0.w,A1.x,A1.y,A1.z,A1.w};
      float v1[8] = {B0.x,B0.y,B0.z,B0.w,B1.x,B1.y,B1.z,B1.w};
      #pragma unroll
      for (int qq = 0; qq < 8; qq++){
        int wloc = w0 + ch*8 + qq;
        *(uint32*)&slab[(r*64 + wloc)*68 + c0] = (bf16r(v1[qq]) << 16) | bf16r(v0[qq]);
      }
    }
  }
  int ob = t >> 1;
  int kh16 = (t & 1)*16;
  const ushort16* wrow = wnb + (size_t)ob*CKn + kh16;
  {
    uint4 bA = *(const uint4*)(wrow);
    uint4 bB = *(const uint4*)(wrow + 8);
    ushort16* dst = &Bl[0][ob*36 + kh16];
    ((uint2*)dst)[0] = make_uint2(bA.x, bA.y);
    ((uint2*)dst)[1] = make_uint2(bA.z, bA.w);
    ((uint2*)dst)[2] = make_uint2(bB.x, bB.y);
    ((uint2*)dst)[3] = make_uint2(bB.z, bB.w);
  }
  int quad8 = (lane >> 4) << 3;
  int iT[2], jT[2];
  #pragma unroll
  for (int mt = 0; mt < 2; mt++){
    int m = wv*32 + mt*16 + (lane & 15);
    int pos = m < 124 ? m : 123;
    int hi = pos >= 62;
    iT[mt] = hi;
    jT[mt] = pos - (hi ? 62 : 0);
  }
  floatx4 acc[2][8];
  #pragma unroll
  for (int mt = 0; mt < 2; mt++)
    #pragma unroll
    for (int nt = 0; nt < 8; nt++)
      acc[mt][nt] = (floatx4){0.f, 0.f, 0.f, 0.f};
  union U8 { uint2 u[2]; bf16x8 v; };
  for (int s = 0; s < 18; s++){
    uint4 nA, nB;
    if (s < 17){
      nA = *(const uint4*)(wrow + (s+1)*32);
      nB = *(const uint4*)(wrow + (s+1)*32 + 8);
    }
    __syncthreads();
    int k0 = s*32 + quad8;
    int q = k0 >> 6;
    int c0 = k0 & 63;
    int kh = (q*86) >> 8;
    int kw = q - kh*3;
    bf16x8 af[2];
    #pragma unroll
    for (int mt = 0; mt < 2; mt++){
      const ushort16* ap = &slab[((iT[mt] + kh)*64 + jT[mt] + kw)*68 + c0];
      U8 ua;
      ua.u[0] = *(const uint2*)(ap);
      ua.u[1] = *(const uint2*)(ap + 4);
      af[mt] = ua.v;
    }
    const ushort16* bbase = &Bl[s & 1][(lane & 15)*36 + quad8];
    bf16x8 bf[8];
    #pragma unroll
    for (int nt = 0; nt < 8; nt++){
      const ushort16* bp = bbase + nt*576;
      U8 ub;
      ub.u[0] = *(const uint2*)(bp);
      ub.u[1] = *(const uint2*)(bp + 4);
      bf[nt] = ub.v;
    }
    #pragma unroll
    for (int mt = 0; mt < 2; mt++)
      #pragma unroll
      for (int nt = 0; nt < 8; nt++)
        acc[mt][nt] = __builtin_amdgcn_mfma_f32_16x16x32_bf16(af[mt], bf[nt], acc[mt][nt], 0, 0, 0);
    if (s < 17){
      ushort16* dst = &Bl[(s+1) & 1][ob*36 + kh16];
      ((uint2*)dst)[0] = make_uint2(nA.x, nA.y);
      ((uint2*)dst)[1] = make_uint2(nA.z, nA.w);
      ((uint2*)dst)[2] = make_uint2(nB.x, nB.y);
      ((uint2*)dst)[3] = make_uint2(nB.z, nB.w);
    }
  }
  float bv[8];
  #pragma unroll
  for (int nt = 0; nt < 8; nt++) bv[nt] = bias[nt*16 + (lane & 15)];
  // ---- coalesced epilogue via LDS transpose ----
  float* ytile = (float*)slab;            // 64 x 130 floats = 33280 B (slab is 34816 B)
  int cl = lane & 15;
  int quad = lane >> 4;
  #pragma unroll
  for (int chunk = 0; chunk < 2; chunk++){
    __syncthreads();
    #pragma unroll
    for (int nt4 = 0; nt4 < 4; nt4++){
      int nt = chunk*4 + nt4;
      int ol = nt4*16 + cl;
      #pragma unroll
      for (int mt = 0; mt < 2; mt++){
        #pragma unroll
        for (int reg = 0; reg < 4; reg++){
          int m = wv*32 + mt*16 + quad*4 + reg;
          if (m < 124) ytile[ol*130 + m] = acc[mt][nt][reg] + bv[nt];
        }
      }
    }
    __syncthreads();
    #pragma unroll
    for (int r = 0; r < 16; r++){
      int ol = wv*16 + r;
      int o = chunk*64 + ol;
      if (lane < 62){
        float2 v = *(float2*)&ytile[ol*130 + lane*2];
        *(float2*)&y[((size_t)b*On + o)*Ln + (size_t)i0*WP + lane*2] = v;
      }
    }
  }
}

// softmax v3: register-resident y (R6 win).
__global__ __launch_bounds__(256, 4) void k_softp(const float* __restrict__ y, ushort16* __restrict__ pb,
                                                  float* __restrict__ S1, float* __restrict__ S2){
  __shared__ float mpart[2][256], dpart[2][256];
  __shared__ float s1loc[128], s2loc[128];
  int b = blockIdx.x;
  int s = blockIdx.y;          // 0..30
  int i0 = s*2;
  int t = threadIdx.x;
  int j = t & 63;
  int og = t >> 6;
  if (t < 128){ s1loc[t] = 0.f; s2loc[t] = 0.f; }
  int je = j < WP ? j : (WP-1);
  const float* yb = y + ((size_t)b*On + og*32)*Ln + (size_t)i0*WP + je;
  float v0[32], v1[32];
  #pragma unroll
  for (int oi = 0; oi < 32; oi++){
    const float* yp = yb + (size_t)oi*Ln;
    v0[oi] = yp[0];
    v1[oi] = yp[WP];
  }
  float m0 = v0[0], m1 = v1[0];
  #pragma unroll
  for (int oi = 1; oi < 32; oi++){
    m0 = fmaxf(m0, v0[oi]);
    m1 = fmaxf(m1, v1[oi]);
  }
  float d0 = 0.f, d1 = 0.f;
  #pragma unroll
  for (int oi = 0; oi < 32; oi++){
    v0[oi] = __expf(v0[oi] - m0); d0 += v0[oi];
    v1[oi] = __expf(v1[oi] - m1); d1 += v1[oi];
  }
  mpart[0][t] = m0; dpart[0][t] = d0;
  mpart[1][t] = m1; dpart[1][t] = d1;
  __syncthreads();
  float scl[2];
  {
    float ml[2] = {m0, m1};
    #pragma unroll
    for (int r = 0; r < 2; r++){
      float ma = mpart[r][j],      mb = mpart[r][64+j];
      float mcc = mpart[r][128+j], md = mpart[r][192+j];
      float mm = fmaxf(fmaxf(ma, mb), fmaxf(mcc, md));
      float dd = dpart[r][j]*__expf(ma-mm) + dpart[r][64+j]*__expf(mb-mm)
               + dpart[r][128+j]*__expf(mcc-mm) + dpart[r][192+j]*__expf(md-mm);
      scl[r] = __expf(ml[r]-mm) / dd;
    }
  }
  bool act = j < WP;
  float sc0 = act ? scl[0] : 0.f;
  float sc1 = act ? scl[1] : 0.f;
  ushort16* ppb = pb + (((size_t)b*On + og*32)*HP + i0)*64 + j;
  #pragma unroll
  for (int oi = 0; oi < 32; oi++){
    float r0 = v0[oi]*sc0;
    float r1 = v1[oi]*sc1;
    float p0 = r0*r0, p1 = r1*r1;
    ushort16* pp = ppb + (size_t)oi*(HP*64);
    pp[0]  = (ushort16)bf16r(p0);
    pp[64] = (ushort16)bf16r(p1);
    float s1v = r0 + r1, s2v = p0 + p1;
    #pragma unroll
    for (int off = 32; off; off >>= 1){ s1v += __shfl_down(s1v, off); s2v += __shfl_down(s2v, off); }
    if (j == 0){ s1loc[og*32 + oi] += s1v; s2loc[og*32 + oi] += s2v; }
  }
  __syncthreads();
  if (t < 128){ atomicAdd(&S1[t], s1loc[t]); atomicAdd(&S2[t], s2loc[t]); }
}

// MFMA delta v6: i-split for 2 blocks/CU.
// R6 post-mortem: grid was 256 blocks = 1 block/CU; 2 barriers/iter with no
// co-resident block -> stage/compute fully serialized, all pipes <13% busy,
// occupancy 19%. Fix: split the 31-iter i-loop across khalf (16/15 iters),
// grid (8, 32, 2) = 512 blocks = 2/CU -> inter-block overlap fills barrier
// gaps. Epilogue atomics 2.36M -> 4.72M at 16-way (same 4 proven G stripes).
#define DOKH2(av, dc, ec, off) { \
  U16 f0, f1, f2; \
  f0.q = dc; \
  f1.q = make_uint4((dc.x>>16)|(dc.y<<16), (dc.y>>16)|(dc.z<<16), \
                    (dc.z>>16)|(dc.w<<16), (dc.w>>16)|(ec<<16)); \
  f2.q = make_uint4(dc.y, dc.z, dc.w, ec); \
  acc[(off)+0] = __builtin_amdgcn_mfma_f32_16x16x32_bf16(av, f0.v, acc[(off)+0], 0, 0, 0); \
  acc[(off)+1] = __builtin_amdgcn_mfma_f32_16x16x32_bf16(av, f1.v, acc[(off)+1], 0, 0, 0); \
  acc[(off)+2] = __builtin_amdgcn_mfma_f32_16x16x32_bf16(av, f2.v, acc[(off)+2], 0, 0, 0); \
}

__global__ __launch_bounds__(512, 2) void k_deltam(const ushort16* __restrict__ xb,
                                                   const ushort16* __restrict__ pb,
                                                   float* __restrict__ G){
  __shared__ uint4 lds4[36864/16];
  char* ldsb = (char*)lds4;
  int t = threadIdx.x;
  int lane = t & 63;
  int wv = t >> 6;          // 0..7
  int mgl = wv & 3;
  int ih  = wv >> 2;
  int bx  = blockIdx.x;     // 0..7: ntk = bx&3, khalf = bx>>2
  int ntk = bx & 3;
  int khalf = bx >> 2;
  int b   = blockIdx.y;
  int oh  = blockIdx.z;
  int it0 = khalf*16;
  int nit = khalf ? 15 : 16;
  int cl = lane & 15;
  int quad = lane >> 4;
  int quad8 = quad << 3;

  int o128 = t >> 2;
  int sP = o128 >> 6;
  int oP = o128 & 63;
  int segP = t & 3;
  const ushort16* pbase = pb + ((size_t)b*On + oh*64 + oP)*(HP*64) + segP*16;
  int pIrow = sP*31 + it0;
  char* pwr = ldsb + (sP*64 + oP)*128;
  int psw0 = ((2*segP)     ^ (oP & 7)) << 4;
  int psw1 = ((2*segP + 1) ^ (oP & 7)) << 4;
  int pX = t & 7;
  int r1 = t >> 3;
  int s1_ = (r1 >= 48) ? 1 : 0;
  int rr1 = r1 - s1_*48;
  int c1 = rr1/3, kh1 = rr1 - c1*3;
  int rr2 = (64 + (t >> 3)) - 48;
  int c2 = rr2/3, kh2 = rr2 - c2*3;
  const ushort16* xbb = xb + ((size_t)b*Cn + ntk*16)*(Hn*Wn) + pX*8;
  const ushort16* x1base = xbb + (size_t)c1*(Hn*Wn);
  const ushort16* x2base = xbb + (size_t)c2*(Hn*Wn);
  int x1Irow = s1_*31 + kh1 + it0;
  int x2Irow = 31 + kh2 + it0;
  char* x1wr = ldsb + 16384 + (s1_*48 + c1*3 + kh1)*144 + pX*16;
  char* x2wr = ldsb + 16384 + (48    + c2*3 + kh2)*144 + pX*16;

  if (t < 96) *(uint4*)(ldsb + 16384 + t*144 + 128) = make_uint4(0,0,0,0);

  const char* ptb = ldsb + ih*8192;
  const char* xtb = ldsb + 16384 + ih*6912;
  int orow = mgl*16 + cl;
  int o7 = cl & 7;

  floatx4 acc[9];
  #pragma unroll
  for (int nt = 0; nt < 9; nt++) acc[nt] = (floatx4){0.f, 0.f, 0.f, 0.f};
  union U16 { uint4 q; bf16x8 v; };

  uint4 pr0, pr1, xr0, xr1;
  {
    const ushort16* prow = pbase + (size_t)(pIrow + 0)*64;
    pr0 = *(const uint4*)(prow);
    pr1 = *(const uint4*)(prow + 8);
    xr0 = *(const uint4*)(x1base + (size_t)(x1Irow + 0)*Wn);
    if (t < 256) xr1 = *(const uint4*)(x2base + (size_t)(x2Irow + 0)*Wn);
  }

  for (int it = 0; it < nit; ++it){
    __syncthreads();
    *(uint4*)(pwr + psw0) = pr0;
    *(uint4*)(pwr + psw1) = pr1;
    *(uint4*)(x1wr) = xr0;
    if (t < 256) *(uint4*)(x2wr) = xr1;
    if (it < nit-1){
      const ushort16* prow = pbase + (size_t)(pIrow + it + 1)*64;
      pr0 = *(const uint4*)(prow);
      pr1 = *(const uint4*)(prow + 8);
      xr0 = *(const uint4*)(x1base + (size_t)(x1Irow + it + 1)*Wn);
      if (t < 256) xr1 = *(const uint4*)(x2base + (size_t)(x2Irow + it + 1)*Wn);
    }
    __syncthreads();
    #pragma unroll
    for (int sl = 0; sl < 2; sl++){
      U16 a;
      a.q = *(const uint4*)(ptb + orow*128 + (((sl*4 + quad) ^ o7) << 4));
      #pragma unroll
      for (int kh = 0; kh < 3; kh++){
        const char* rb = xtb + (cl*3 + kh)*144;
        uint4 d = *(const uint4*)(rb + ((sl*32 + quad8) << 1));
        uint32 e = *(const uint32*)(rb + ((sl*32 + quad8 + 8) << 1));
        DOKH2(a.v, d, e, kh*3)
      }
    }
  }

  __syncthreads();
  float* sc = (float*)ldsb;
  if (ih == 1){
    #pragma unroll
    for (int nt = 0; nt < 9; nt++)
      #pragma unroll
      for (int reg = 0; reg < 4; reg++)
        sc[(mgl*16 + quad*4 + reg)*144 + nt*16 + cl] = acc[nt][reg];
  }
  __syncthreads();
  if (ih == 0){
    float* Gq = G + (size_t)(b & 3)*GSZ;
    #pragma unroll
    for (int nt = 0; nt < 9; nt++)
      #pragma unroll
      for (int reg = 0; reg < 4; reg++){
        int ol = mgl*16 + quad*4 + reg;
        int og = oh*64 + ol;
        float v = acc[nt][reg] + sc[ol*144 + nt*16 + cl];
        atomicAdd(&Gq[(size_t)og*CKn + nt*64 + ntk*16 + cl], v);
      }
  }
}

__global__ __launch_bounds__(576) void k_finalm(const float* __restrict__ w, const float* __restrict__ G,
                                                const float* __restrict__ S1, const float* __restrict__ S2,
                                                float* __restrict__ dw){
  int o = blockIdx.x; int k = threadIdx.x;
  int c = k / 9;
  int q = k - c*9;
  float s1 = S1[o]; if (s1 == 0.f) s1 = 1.f;
  float g = 0.f;
  #pragma unroll
  for (int kq = 0; kq < KSB; kq++) g += G[(size_t)kq*GSZ + o*CKn + q*64 + c];
  dw[o*CKn + k] = (g - S2[o]*w[o*CKn + k]) / s1;
}

// ---------------- old fallback path ----------------
__global__ __launch_bounds__(256) void k_soft_old(const float* __restrict__ y, float* __restrict__ mbuf,
                                                  float* __restrict__ invdbuf, float* __restrict__ S1,
                                                  float* __restrict__ S2){
  __shared__ float s1loc[128], s2loc[128];
  int t = threadIdx.x;
  if (t < 128){ s1loc[t] = 0.f; s2loc[t] = 0.f; }
  __syncthreads();
  int b = blockIdx.x;
  int i = blockIdx.y*4 + (t >> 6);
  int j = t & 63;
  bool act = (i < 62) && (j < 62);
  const float* yp = y + (((size_t)b*On)*HP + (i < 62 ? i : 0))*WP + j;
  float mx = -3.0e38f;
  if (act){ for (int o = 0; o < On; o++) mx = fmaxf(mx, yp[(size_t)o*Ln]); }
  float den = 0.f;
  if (act){ for (int o = 0; o < On; o++) den += __expf(yp[(size_t)o*Ln] - mx); }
  float inv = act ? 1.f/den : 0.f;
  if (act){
    int pos = (b*HP + i)*WP + j;
    mbuf[pos] = mx; invdbuf[pos] = inv;
  }
  for (int o = 0; o < On; o++){
    float r = act ? __expf(yp[(size_t)o*Ln] - mx)*inv : 0.f;
    float s1v = r, s2v = r*r;
    #pragma unroll
    for (int off = 32; off; off >>= 1){ s1v += __shfl_down(s1v, off); s2v += __shfl_down(s2v, off); }
    if ((t & 63) == 0){ atomicAdd(&s1loc[o], s1v); atomicAdd(&s2loc[o], s2v); }
  }
  __syncthreads();
  if (t < 128){ atomicAdd(&S1[t], s1loc[t]); atomicAdd(&S2[t], s2loc[t]); }
}

__global__ __launch_bounds__(256) void k_delta_old(const float* __restrict__ x, const float* __restrict__ y,
                                                   const float* __restrict__ mbuf, const float* __restrict__ invdbuf,
                                                   float* __restrict__ G){
  __shared__ float planes[3][64][64];
  __shared__ float plds[16][64];
  int o0 = blockIdx.x * 16;
  int bs = blockIdx.y;
  int b = bs >> 2;
  int s = bs & 3;
  int i0 = s * 16;
  int nrows = (s == 3) ? 14 : 16;
  int t = threadIdx.x;
  int lane = t & 63;
  int w = t >> 6;
  int lc = t >> 2;
  int lw0 = (t & 3) << 4;
  const float* xb = x + (size_t)b*(Cn*Hn*Wn) + (size_t)lc*(Hn*Wn) + lw0;
  float acc[4][9];
  #pragma unroll
  for (int oi = 0; oi < 4; oi++)
    #pragma unroll
    for (int q = 0; q < 9; q++) acc[oi][q] = 0.f;
  #pragma unroll
  for (int pp = 0; pp < 2; pp++){
    int ih = i0 + pp;
    const float* src = xb + (size_t)ih*Wn;
    #pragma unroll
    for (int q = 0; q < 16; q++) planes[ih % 3][lw0 + q][lc] = src[q];
  }
  for (int ii = 0; ii < nrows; ii++){
    int i = i0 + ii;
    {
      int ih = i + 2;
      const float* src = xb + (size_t)ih*Wn;
      #pragma unroll
      for (int q = 0; q < 16; q++) planes[ih % 3][lw0 + q][lc] = src[q];
    }
    int R = b*HP + i;
    #pragma unroll
    for (int oi = 0; oi < 4; oi++){
      int o = o0 + w*4 + oi;
      float p = 0.f;
      if (lane < WP){
        int pos = R*WP + lane;
        float yv = y[(((size_t)b*On + o)*HP + i)*WP + lane];
        float r = __expf(yv - mbuf[pos]) * invdbuf[pos];
        p = r*r;
      }
      plds[w*4 + oi][lane] = p;
    }
    __syncthreads();
    int c = lane;
    int s0 = i % 3, s1 = (i+1) % 3, s2g = (i+2) % 3;
    #pragma unroll 1
    for (int jj0 = 0; jj0 < 56; jj0 += 8){
      float xv[3][12];
      #pragma unroll
      for (int q = 0; q < 12; q++){
        xv[0][q] = planes[s0][jj0+q][c];
        xv[1][q] = planes[s1][jj0+q][c];
        xv[2][q] = planes[s2g][jj0+q][c];
      }
      #pragma unroll
      for (int oi = 0; oi < 4; oi++){
        float4 pa = *(const float4*)&plds[w*4+oi][jj0];
        float4 pbq = *(const float4*)&plds[w*4+oi][jj0+4];
        float pv[8] = {pa.x,pa.y,pa.z,pa.w,pbq.x,pbq.y,pbq.z,pbq.w};
        #pragma unroll
        for (int kh = 0; kh < 3; kh++)
          #pragma unroll
          for (int kw = 0; kw < 3; kw++)
            #pragma unroll
            for (int dj = 0; dj < 8; dj++)
              acc[oi][kh*3+kw] += pv[dj]*xv[kh][dj+kw];
      }
    }
    {
      float xv[3][12];
      #pragma unroll
      for (int q = 0; q < 12; q++){
        bool ok = (56 + q) < 64;
        xv[0][q] = ok ? planes[s0][56+q][c] : 0.f;
        xv[1][q] = ok ? planes[s1][56+q][c] : 0.f;
        xv[2][q] = ok ? planes[s2g][56+q][c] : 0.f;
      }
      #pragma unroll
      for (int oi = 0; oi < 4; oi++){
        float4 pa = *(const float4*)&plds[w*4+oi][56];
        float4 pbq = *(const float4*)&plds[w*4+oi][60];
        float pv[8] = {pa.x,pa.y,pa.z,pa.w,pbq.x,pbq.y,pbq.z,pbq.w};
        #pragma unroll
        for (int kh = 0; kh < 3; kh++)
          #pragma unroll
          for (int kw = 0; kw < 3; kw++)
            #pragma unroll
            for (int dj = 0; dj < 8; dj++)
              acc[oi][kh*3+kw] += pv[dj]*xv[kh][dj+kw];
      }
    }
    __syncthreads();
  }
  #pragma unroll
  for (int oi = 0; oi < 4; oi++){
    float* Gr = G + (size_t)(o0 + w*4 + oi)*CKn + lane*9;
    #pragma unroll
    for (int q = 0; q < 9; q++) atomicAdd(&Gr[q], acc[oi][q]);
  }
}

__global__ __launch_bounds__(576) void k_final_old(const float* __restrict__ w, const float* __restrict__ G,
                                                   const float* __restrict__ S1, const float* __restrict__ S2,
                                                   float* __restrict__ dw){
  int o = blockIdx.x; int k = threadIdx.x;
  float s1 = S1[o]; if (s1 == 0.f) s1 = 1.f;
  dw[o*CKn + k] = (G[o*CKn + k] - S2[o]*w[o*CKn + k]) / s1;
}

extern "C" void kernel_launch(void* const* d_in, const int* in_sizes, int n_in,
                              void* d_out, int out_size, void* d_ws, size_t ws_size,
                              hipStream_t stream){
  const float* x    = (const float*)d_in[0];
  const float* w    = (const float*)d_in[1];
  const float* bias = (const float*)d_in[2];
  float* y  = (float*)d_out;
  float* dw = (float*)d_out + Y_ELEMS;
  float* ws = (float*)d_ws;

  if (ws_size >= WS_NEED){
    float* S1 = ws + NS1;
    float* S2 = ws + NS2;
    float* G  = ws + NG;
    ushort16* wnb = (ushort16*)(ws + NWNB);
    ushort16* xb  = (ushort16*)(ws + NXB);
    ushort16* pb  = (ushort16*)(ws + NPB);
    k_norm  <<<dim3(On),      dim3(256), 0, stream>>>(w, wnb, S1, S2, G, KSB);
    k_xb    <<<dim3(8192),    dim3(256), 0, stream>>>(x, xb);
    k_convm <<<dim3(31, Bn),  dim3(256), 0, stream>>>(x, wnb, bias, y);
    k_softp <<<dim3(Bn, 31),  dim3(256), 0, stream>>>(y, pb, S1, S2);
    k_deltam<<<dim3(8, Bn, 2), dim3(512), 0, stream>>>(xb, pb, G);
    k_finalm<<<dim3(On),      dim3(CKn), 0, stream>>>(w, G, S1, S2, dw);
  } else {
    float* S1   = ws + 73728;
    float* S2   = ws + 73856;
    float* G    = ws + 73984;
    float* mbuf = ws + 147712;
    float* invd = ws + 270720;
    ushort16* wnb = (ushort16*)(ws + 393728);
    k_norm     <<<dim3(On),      dim3(256), 0, stream>>>(w, wnb, S1, S2, G, 1);
    k_convm    <<<dim3(31, Bn),  dim3(256), 0, stream>>>(x, wnb, bias, y);
    k_soft_old <<<dim3(Bn, 16),  dim3(256), 0, stream>>>(y, mbuf, invd, S1, S2);
    k_delta_old<<<dim3(8, Bn*4), dim3(256), 0, stream>>>(x, y, mbuf, invd, G);
    k_final_old<<<dim3(On),      dim3(CKn), 0, stream>>>(w, G, S1, S2, dw);
  }
}